// Round 1
// baseline (599.920 us; speedup 1.0000x reference)
//
#include <hip/hip_runtime.h>
#include <math.h>

#define N_TOK 8192
#define DM 1024
#define NE 8
#define HE 512
#define NPAIR 16384

#define BM 128
#define BN 128
#define BK 64
#define LDT 72   // padded LDS row stride (elems): 144B -> breaks 16-way bank aliasing

typedef __bf16 bf16x8 __attribute__((ext_vector_type(8)));
typedef float f32x4 __attribute__((ext_vector_type(4)));

__device__ __forceinline__ unsigned short f2bf(float f) {
    unsigned int u = __float_as_uint(f);
    u += 0x7fffu + ((u >> 16) & 1u);   // RNE; inputs finite
    return (unsigned short)(u >> 16);
}

__device__ __forceinline__ float gelu_exact(float v) {
    return 0.5f * v * (1.0f + erff(v * 0.70710678118654752440f));
}

__device__ __forceinline__ double shfl_xor_dbl(double v, int m) {
    long long l = __double_as_longlong(v);
    int lo = (int)(l & 0xffffffffll);
    int hi = (int)(l >> 32);
    lo = __shfl_xor(lo, m, 64);
    hi = __shfl_xor(hi, m, 64);
    return __longlong_as_double(((long long)hi << 32) | (unsigned long long)(unsigned int)lo);
}

// ---------------- cast x fp32 -> bf16 ----------------
__global__ void cast_x_kernel(const float* __restrict__ x, unsigned short* __restrict__ xb) {
    int i = blockIdx.x * 256 + threadIdx.x;   // covers 2,097,152 float4s
    float4 v = ((const float4*)x)[i];
    ushort4 o;
    o.x = f2bf(v.x); o.y = f2bf(v.y); o.z = f2bf(v.z); o.w = f2bf(v.w);
    ((ushort4*)xb)[i] = o;
}

// ------- per-expert transpose+cast: src fp32 [R][C] -> dst bf16 [C][R] -------
__global__ void transpose_cast_kernel(const float* __restrict__ src,
                                      unsigned short* __restrict__ dst,
                                      int R, int C) {
    __shared__ float tile[64][65];
    const float* s = src + (size_t)blockIdx.z * R * C;
    unsigned short* d = dst + (size_t)blockIdx.z * R * C;
    int c0 = blockIdx.x * 64, r0 = blockIdx.y * 64;
    int tc = threadIdx.x & 63, tg = threadIdx.x >> 6;
    #pragma unroll
    for (int i = 0; i < 16; i++) {
        int r = tg * 16 + i;
        tile[r][tc] = s[(size_t)(r0 + r) * C + (c0 + tc)];
    }
    __syncthreads();
    #pragma unroll
    for (int i = 0; i < 16; i++) {
        int r = tg * 16 + i;
        d[(size_t)(c0 + r) * R + (r0 + tc)] = f2bf(tile[tc][r]);
    }
}

// ---------------- gating: softmax + top2 (double precision) ----------------
__global__ void gate_kernel(const float* __restrict__ x, const float* __restrict__ gw,
                            float* __restrict__ w_tok, int* __restrict__ e_sel,
                            int* __restrict__ cnt) {
    int n = blockIdx.x * 4 + (threadIdx.x >> 6);
    int lane = threadIdx.x & 63;
    const float* xr = x + (size_t)n * DM;
    double s[NE];
    #pragma unroll
    for (int e = 0; e < NE; e++) s[e] = 0.0;
    for (int i = 0; i < DM / 64; i++) {
        int d = i * 64 + lane;
        float xv = xr[d];
        const float* g = gw + (size_t)d * NE;
        #pragma unroll
        for (int e = 0; e < NE; e++) s[e] += (double)xv * (double)g[e];
    }
    #pragma unroll
    for (int e = 0; e < NE; e++) {
        for (int off = 32; off > 0; off >>= 1)
            s[e] += shfl_xor_dbl(s[e], off);
    }
    if (lane == 0) {
        double m = s[0];
        for (int e = 1; e < NE; e++) if (s[e] > m) m = s[e];
        double sum = 0.0;
        for (int e = 0; e < NE; e++) sum += exp(s[e] - m);
        int i1 = 0; double v1 = s[0];
        for (int e = 1; e < NE; e++) if (s[e] > v1) { v1 = s[e]; i1 = e; }
        int i2 = -1; double v2 = -1e300;
        for (int e = 0; e < NE; e++) if (e != i1 && s[e] > v2) { v2 = s[e]; i2 = e; }
        w_tok[n] = (float)((exp(v1 - m) + exp(v2 - m)) / sum);
        e_sel[2 * n]     = i1;
        e_sel[2 * n + 1] = i2;
        atomicAdd(&cnt[i1], 1);
        atomicAdd(&cnt[i2], 1);
    }
}

// ---------------- tiny exclusive scan over 8 experts ----------------
__global__ void scan_kernel(const int* __restrict__ cnt, int* __restrict__ offs,
                            int* __restrict__ cursor) {
    if (threadIdx.x == 0) {
        int a = 0;
        for (int e = 0; e < NE; e++) { offs[e] = a; a += cnt[e]; cursor[e] = 0; }
    }
}

// ---------------- scatter tokens into packed per-expert lists ----------------
__global__ void scatter_kernel(const int* __restrict__ e_sel, const int* __restrict__ offs,
                               int* __restrict__ cursor, int* __restrict__ pair_tok) {
    int n = blockIdx.x * 256 + threadIdx.x;
    if (n >= N_TOK) return;
    #pragma unroll
    for (int k = 0; k < 2; k++) {
        int e = e_sel[2 * n + k];
        int pos = atomicAdd(&cursor[e], 1);
        pair_tok[offs[e] + pos] = n;
    }
}

// ---------------- GEMM1: h = gelu(x_gathered @ w1[e] + b1[e]) ----------------
__global__ __launch_bounds__(256, 2) void gemm1_kernel(
        const unsigned short* __restrict__ xb,      // [N_TOK][DM] bf16
        const unsigned short* __restrict__ w1t,     // [E][HE][DM] bf16 (B^T layout)
        const float* __restrict__ b1,               // [E][HE]
        const int* __restrict__ pair_tok,
        const int* __restrict__ cnt, const int* __restrict__ offs,
        unsigned short* __restrict__ hbuf) {        // [NPAIR][HE] bf16
    int e = blockIdx.z;
    int cn = cnt[e];
    int m0 = blockIdx.y * BM;
    if (m0 >= cn) return;
    int n0 = blockIdx.x * BN;
    int base = offs[e];

    __shared__ __align__(16) unsigned short As[BM * LDT];
    __shared__ __align__(16) unsigned short Bs[BN * LDT];
    __shared__ int tks[BM];

    int tid = threadIdx.x;
    if (tid < BM) {
        int r = m0 + tid;
        tks[tid] = pair_tok[base + (r < cn ? r : 0)];
    }

    const unsigned short* wB = w1t + (size_t)e * (HE * DM) + (size_t)n0 * DM;

    int lane = tid & 63;
    int wave = tid >> 6;
    int wm = (wave & 1) * 64;
    int wn = (wave >> 1) * 64;
    int fr = lane & 15;
    int fq = lane >> 4;

    f32x4 acc[4][4];
    #pragma unroll
    for (int i = 0; i < 4; i++)
        #pragma unroll
        for (int j = 0; j < 4; j++)
            acc[i][j] = (f32x4){0.f, 0.f, 0.f, 0.f};

    int lr = tid >> 3;
    int lc = (tid & 7) * 8;

    for (int k0 = 0; k0 < DM; k0 += BK) {
        __syncthreads();
        #pragma unroll
        for (int p = 0; p < 4; p++) {
            int r = lr + p * 32;
            int t = tks[r];
            *(uint4*)(&As[r * LDT + lc]) = *(const uint4*)(&xb[(size_t)t * DM + k0 + lc]);
            *(uint4*)(&Bs[r * LDT + lc]) = *(const uint4*)(&wB[(size_t)r * DM + k0 + lc]);
        }
        __syncthreads();
        #pragma unroll
        for (int kk = 0; kk < BK; kk += 32) {
            bf16x8 af[4], bfv[4];
            #pragma unroll
            for (int i = 0; i < 4; i++)
                af[i] = *(const bf16x8*)(&As[(wm + i * 16 + fr) * LDT + kk + fq * 8]);
            #pragma unroll
            for (int j = 0; j < 4; j++)
                bfv[j] = *(const bf16x8*)(&Bs[(wn + j * 16 + fr) * LDT + kk + fq * 8]);
            #pragma unroll
            for (int i = 0; i < 4; i++)
                #pragma unroll
                for (int j = 0; j < 4; j++)
                    acc[i][j] = __builtin_amdgcn_mfma_f32_16x16x32_bf16(af[i], bfv[j], acc[i][j], 0, 0, 0);
        }
    }

    #pragma unroll
    for (int j = 0; j < 4; j++) {
        int nn = n0 + wn + j * 16 + fr;          // h index (C/D col = lane&15)
        float bias = b1[e * HE + nn];
        #pragma unroll
        for (int i = 0; i < 4; i++) {
            #pragma unroll
            for (int r = 0; r < 4; r++) {
                int mm = wm + i * 16 + fq * 4 + r;  // C/D row = quad*4+reg
                if (m0 + mm < cn) {
                    float v = acc[i][j][r] + bias;
                    hbuf[(size_t)(base + m0 + mm) * HE + nn] = f2bf(gelu_exact(v));
                }
            }
        }
    }
}

// ---------------- GEMM2: out[tok] += w_tok * (h @ w2[e] + b2[e]) ----------------
__global__ __launch_bounds__(256, 2) void gemm2_kernel(
        const unsigned short* __restrict__ hbuf,    // [NPAIR][HE] bf16
        const unsigned short* __restrict__ w2t,     // [E][DM][HE] bf16 (B^T layout)
        const float* __restrict__ b2,               // [E][DM]
        const int* __restrict__ pair_tok,
        const float* __restrict__ w_tok,
        const int* __restrict__ cnt, const int* __restrict__ offs,
        float* __restrict__ out) {
    int e = blockIdx.z;
    int cn = cnt[e];
    int m0 = blockIdx.y * BM;
    if (m0 >= cn) return;
    int n0 = blockIdx.x * BN;
    int base = offs[e];

    __shared__ __align__(16) unsigned short As[BM * LDT];
    __shared__ __align__(16) unsigned short Bs[BN * LDT];
    __shared__ int tks[BM];
    __shared__ float wts[BM];

    int tid = threadIdx.x;
    if (tid < BM) {
        int r = m0 + tid;
        int rr = (r < cn ? r : cn - 1);
        int t = pair_tok[base + rr];
        tks[tid] = t;
        wts[tid] = w_tok[t];
    }

    const unsigned short* wB = w2t + (size_t)e * (DM * HE) + (size_t)n0 * HE;
    const unsigned short* aB = hbuf + (size_t)(base + m0) * HE;

    int lane = tid & 63;
    int wave = tid >> 6;
    int wm = (wave & 1) * 64;
    int wn = (wave >> 1) * 64;
    int fr = lane & 15;
    int fq = lane >> 4;

    f32x4 acc[4][4];
    #pragma unroll
    for (int i = 0; i < 4; i++)
        #pragma unroll
        for (int j = 0; j < 4; j++)
            acc[i][j] = (f32x4){0.f, 0.f, 0.f, 0.f};

    int lr = tid >> 3;
    int lc = (tid & 7) * 8;

    for (int k0 = 0; k0 < HE; k0 += BK) {
        __syncthreads();
        #pragma unroll
        for (int p = 0; p < 4; p++) {
            int r = lr + p * 32;
            int ar = (m0 + r < cn) ? r : 0;
            *(uint4*)(&As[r * LDT + lc]) = *(const uint4*)(&aB[(size_t)ar * HE + k0 + lc]);
            *(uint4*)(&Bs[r * LDT + lc]) = *(const uint4*)(&wB[(size_t)r * HE + k0 + lc]);
        }
        __syncthreads();
        #pragma unroll
        for (int kk = 0; kk < BK; kk += 32) {
            bf16x8 af[4], bfv[4];
            #pragma unroll
            for (int i = 0; i < 4; i++)
                af[i] = *(const bf16x8*)(&As[(wm + i * 16 + fr) * LDT + kk + fq * 8]);
            #pragma unroll
            for (int j = 0; j < 4; j++)
                bfv[j] = *(const bf16x8*)(&Bs[(wn + j * 16 + fr) * LDT + kk + fq * 8]);
            #pragma unroll
            for (int i = 0; i < 4; i++)
                #pragma unroll
                for (int j = 0; j < 4; j++)
                    acc[i][j] = __builtin_amdgcn_mfma_f32_16x16x32_bf16(af[i], bfv[j], acc[i][j], 0, 0, 0);
        }
    }

    #pragma unroll
    for (int j = 0; j < 4; j++) {
        int dd = n0 + wn + j * 16 + fr;           // output-dim col
        float bias = b2[e * DM + dd];
        #pragma unroll
        for (int i = 0; i < 4; i++) {
            #pragma unroll
            for (int r = 0; r < 4; r++) {
                int mm = wm + i * 16 + fq * 4 + r;
                if (m0 + mm < cn) {
                    int t = tks[mm];
                    float w = wts[mm];
                    atomicAdd(&out[(size_t)t * DM + dd], w * (acc[i][j][r] + bias));
                }
            }
        }
    }
}

extern "C" void kernel_launch(void* const* d_in, const int* in_sizes, int n_in,
                              void* d_out, int out_size, void* d_ws, size_t ws_size,
                              hipStream_t stream) {
    const float* x  = (const float*)d_in[0];
    const float* gw = (const float*)d_in[1];
    const float* w1 = (const float*)d_in[2];
    const float* b1 = (const float*)d_in[3];
    const float* w2 = (const float*)d_in[4];
    const float* b2 = (const float*)d_in[5];
    float* out = (float*)d_out;

    char* ws = (char*)d_ws;
    // ws layout (bytes); total ~48.2 MiB
    unsigned short* xb   = (unsigned short*)(ws);              // 16,777,216
    unsigned short* w1t  = (unsigned short*)(ws + 16777216);   //  8,388,608  [e][h][d]
    unsigned short* w2t  = (unsigned short*)(ws + 25165824);   //  8,388,608  [e][d][h]
    unsigned short* hbuf = (unsigned short*)(ws + 33554432);   // 16,777,216
    float* w_tok         = (float*)(ws + 50331648);            //     32,768
    int*   e_sel         = (int*)(ws + 50364416);              //     65,536
    int*   cnt           = (int*)(ws + 50429952);              //         32
    int*   offs          = (int*)(ws + 50429984);              //         32
    int*   cursor        = (int*)(ws + 50430016);              //         32
    int*   pair_tok      = (int*)(ws + 50430080);              //     65,536

    hipMemsetAsync(cnt, 0, 32, stream);
    hipMemsetAsync(out, 0, (size_t)N_TOK * DM * sizeof(float), stream);

    cast_x_kernel<<<8192, 256, 0, stream>>>(x, xb);
    transpose_cast_kernel<<<dim3(HE / 64, DM / 64, NE), 256, 0, stream>>>(w1, w1t, DM, HE);
    transpose_cast_kernel<<<dim3(DM / 64, HE / 64, NE), 256, 0, stream>>>(w2, w2t, HE, DM);
    gate_kernel<<<N_TOK / 4, 256, 0, stream>>>(x, gw, w_tok, e_sel, cnt);
    scan_kernel<<<1, 64, 0, stream>>>(cnt, offs, cursor);
    scatter_kernel<<<N_TOK / 256, 256, 0, stream>>>(e_sel, offs, cursor, pair_tok);
    gemm1_kernel<<<dim3(HE / BN, N_TOK / BM, NE), 256, 0, stream>>>(
        xb, w1t, b1, pair_tok, cnt, offs, hbuf);
    gemm2_kernel<<<dim3(DM / BN, N_TOK / BM, NE), 256, 0, stream>>>(
        hbuf, w2t, b2, pair_tok, w_tok, cnt, offs, out);
}

// Round 2
// 553.128 us; speedup vs baseline: 1.0846x; 1.0846x over previous
//
#include <hip/hip_runtime.h>
#include <math.h>

#define N_TOK 8192
#define DM 1024
#define NE 8
#define HE 512
#define NPAIR 16384

#define BM 128
#define BN 128
#define BK 64
#define LDT 72   // padded LDS row stride (elems): 144B -> breaks 16-way bank aliasing

#define GSTR 1028  // gate LDS row stride (fp32 elems): 16B-aligned rows, banks spread by 4/expert

typedef __bf16 bf16x8 __attribute__((ext_vector_type(8)));
typedef float f32x4 __attribute__((ext_vector_type(4)));

__device__ __forceinline__ unsigned short f2bf(float f) {
    unsigned int u = __float_as_uint(f);
    u += 0x7fffu + ((u >> 16) & 1u);   // RNE; inputs finite
    return (unsigned short)(u >> 16);
}

__device__ __forceinline__ float bf2f(unsigned short u) {
    return __uint_as_float(((unsigned int)u) << 16);
}

__device__ __forceinline__ float gelu_exact(float v) {
    return 0.5f * v * (1.0f + erff(v * 0.70710678118654752440f));
}

__device__ __forceinline__ double shfl_xor_dbl(double v, int m) {
    long long l = __double_as_longlong(v);
    int lo = (int)(l & 0xffffffffll);
    int hi = (int)(l >> 32);
    lo = __shfl_xor(lo, m, 64);
    hi = __shfl_xor(hi, m, 64);
    return __longlong_as_double(((long long)hi << 32) | (unsigned long long)(unsigned int)lo);
}

// ---------------- cast x fp32 -> bf16 ----------------
__global__ void cast_x_kernel(const float* __restrict__ x, unsigned short* __restrict__ xb) {
    int i = blockIdx.x * 256 + threadIdx.x;   // covers 2,097,152 float4s
    float4 v = ((const float4*)x)[i];
    ushort4 o;
    o.x = f2bf(v.x); o.y = f2bf(v.y); o.z = f2bf(v.z); o.w = f2bf(v.w);
    ((ushort4*)xb)[i] = o;
}

// ------- per-expert transpose+cast: src fp32 [R][C] -> dst bf16 [C][R] -------
__global__ void transpose_cast_kernel(const float* __restrict__ src,
                                      unsigned short* __restrict__ dst,
                                      int R, int C) {
    __shared__ float tile[64][65];
    const float* s = src + (size_t)blockIdx.z * R * C;
    unsigned short* d = dst + (size_t)blockIdx.z * R * C;
    int c0 = blockIdx.x * 64, r0 = blockIdx.y * 64;
    int tc = threadIdx.x & 63, tg = threadIdx.x >> 6;
    #pragma unroll
    for (int i = 0; i < 16; i++) {
        int r = tg * 16 + i;
        tile[r][tc] = s[(size_t)(r0 + r) * C + (c0 + tc)];
    }
    __syncthreads();
    #pragma unroll
    for (int i = 0; i < 16; i++) {
        int r = tg * 16 + i;
        d[(size_t)(c0 + r) * R + (r0 + tc)] = f2bf(tile[tc][r]);
    }
}

// ---------------- gating: softmax + top2 (double precision acc) ----------------
// gw staged transposed into LDS: gls[e][d], row stride GSTR.
// Per wave (1 token): 4 iters x (1 float4 x-load + 8 ds_read_b128 + 32 f64 FMA).
__global__ __launch_bounds__(256) void gate_kernel(
        const float* __restrict__ x, const float* __restrict__ gw,
        float* __restrict__ w_tok, int* __restrict__ e_sel,
        int* __restrict__ cnt) {
    __shared__ float gls[NE * GSTR];
    int tid = threadIdx.x;
    // stage gw [1024][8] -> gls[e][d]  (2048 float4 = 8192 floats)
    for (int v = tid; v < 2048; v += 256) {
        float4 g4 = ((const float4*)gw)[v];
        int idx = v * 4;
        int d = idx >> 3;
        int e0 = idx & 7;   // 0 or 4
        gls[(e0    ) * GSTR + d] = g4.x;
        gls[(e0 + 1) * GSTR + d] = g4.y;
        gls[(e0 + 2) * GSTR + d] = g4.z;
        gls[(e0 + 3) * GSTR + d] = g4.w;
    }
    __syncthreads();

    int n = blockIdx.x * 4 + (tid >> 6);
    int lane = tid & 63;
    const float4* xr = (const float4*)(x + (size_t)n * DM);

    double s[NE];
    #pragma unroll
    for (int e = 0; e < NE; e++) s[e] = 0.0;

    #pragma unroll
    for (int i = 0; i < 4; i++) {
        float4 x4 = xr[i * 64 + lane];
        int d = (i * 64 + lane) * 4;
        #pragma unroll
        for (int e = 0; e < NE; e++) {
            float4 g4 = *(const float4*)(&gls[e * GSTR + d]);
            s[e] += (double)x4.x * (double)g4.x + (double)x4.y * (double)g4.y
                  + (double)x4.z * (double)g4.z + (double)x4.w * (double)g4.w;
        }
    }
    #pragma unroll
    for (int e = 0; e < NE; e++) {
        for (int off = 32; off > 0; off >>= 1)
            s[e] += shfl_xor_dbl(s[e], off);
    }
    if (lane == 0) {
        double m = s[0];
        for (int e = 1; e < NE; e++) if (s[e] > m) m = s[e];
        double sum = 0.0;
        for (int e = 0; e < NE; e++) sum += exp(s[e] - m);
        int i1 = 0; double v1 = s[0];
        for (int e = 1; e < NE; e++) if (s[e] > v1) { v1 = s[e]; i1 = e; }
        int i2 = -1; double v2 = -1e300;
        for (int e = 0; e < NE; e++) if (e != i1 && s[e] > v2) { v2 = s[e]; i2 = e; }
        w_tok[n] = (float)((exp(v1 - m) + exp(v2 - m)) / sum);
        e_sel[2 * n]     = i1;
        e_sel[2 * n + 1] = i2;
        atomicAdd(&cnt[i1], 1);
        atomicAdd(&cnt[i2], 1);
    }
}

// ---------------- tiny exclusive scan over 8 experts ----------------
__global__ void scan_kernel(const int* __restrict__ cnt, int* __restrict__ offs,
                            int* __restrict__ cursor) {
    if (threadIdx.x == 0) {
        int a = 0;
        for (int e = 0; e < NE; e++) { offs[e] = a; a += cnt[e]; cursor[e] = 0; }
    }
}

// ------- scatter tokens into packed per-expert lists + record slot map -------
__global__ void scatter_kernel(const int* __restrict__ e_sel, const int* __restrict__ offs,
                               int* __restrict__ cursor, int* __restrict__ pair_tok,
                               int* __restrict__ slotmap) {
    int n = blockIdx.x * 256 + threadIdx.x;
    if (n >= N_TOK) return;
    #pragma unroll
    for (int k = 0; k < 2; k++) {
        int e = e_sel[2 * n + k];
        int pos = atomicAdd(&cursor[e], 1);
        int slot = offs[e] + pos;
        pair_tok[slot] = n;
        slotmap[2 * n + k] = slot;
    }
}

// ---------------- GEMM1: h = gelu(x_gathered @ w1[e] + b1[e]) ----------------
__global__ __launch_bounds__(256, 2) void gemm1_kernel(
        const unsigned short* __restrict__ xb,      // [N_TOK][DM] bf16
        const unsigned short* __restrict__ w1t,     // [E][HE][DM] bf16 (B^T layout)
        const float* __restrict__ b1,               // [E][HE]
        const int* __restrict__ pair_tok,
        const int* __restrict__ cnt, const int* __restrict__ offs,
        unsigned short* __restrict__ hbuf) {        // [NPAIR][HE] bf16
    int e = blockIdx.z;
    int cn = cnt[e];
    int m0 = blockIdx.y * BM;
    if (m0 >= cn) return;
    int n0 = blockIdx.x * BN;
    int base = offs[e];

    __shared__ __align__(16) unsigned short As[BM * LDT];
    __shared__ __align__(16) unsigned short Bs[BN * LDT];
    __shared__ int tks[BM];

    int tid = threadIdx.x;
    if (tid < BM) {
        int r = m0 + tid;
        tks[tid] = pair_tok[base + (r < cn ? r : 0)];
    }

    const unsigned short* wB = w1t + (size_t)e * (HE * DM) + (size_t)n0 * DM;

    int lane = tid & 63;
    int wave = tid >> 6;
    int wm = (wave & 1) * 64;
    int wn = (wave >> 1) * 64;
    int fr = lane & 15;
    int fq = lane >> 4;

    f32x4 acc[4][4];
    #pragma unroll
    for (int i = 0; i < 4; i++)
        #pragma unroll
        for (int j = 0; j < 4; j++)
            acc[i][j] = (f32x4){0.f, 0.f, 0.f, 0.f};

    int lr = tid >> 3;
    int lc = (tid & 7) * 8;

    for (int k0 = 0; k0 < DM; k0 += BK) {
        __syncthreads();
        #pragma unroll
        for (int p = 0; p < 4; p++) {
            int r = lr + p * 32;
            int t = tks[r];
            *(uint4*)(&As[r * LDT + lc]) = *(const uint4*)(&xb[(size_t)t * DM + k0 + lc]);
            *(uint4*)(&Bs[r * LDT + lc]) = *(const uint4*)(&wB[(size_t)r * DM + k0 + lc]);
        }
        __syncthreads();
        #pragma unroll
        for (int kk = 0; kk < BK; kk += 32) {
            bf16x8 af[4], bfv[4];
            #pragma unroll
            for (int i = 0; i < 4; i++)
                af[i] = *(const bf16x8*)(&As[(wm + i * 16 + fr) * LDT + kk + fq * 8]);
            #pragma unroll
            for (int j = 0; j < 4; j++)
                bfv[j] = *(const bf16x8*)(&Bs[(wn + j * 16 + fr) * LDT + kk + fq * 8]);
            #pragma unroll
            for (int i = 0; i < 4; i++)
                #pragma unroll
                for (int j = 0; j < 4; j++)
                    acc[i][j] = __builtin_amdgcn_mfma_f32_16x16x32_bf16(af[i], bfv[j], acc[i][j], 0, 0, 0);
        }
    }

    #pragma unroll
    for (int j = 0; j < 4; j++) {
        int nn = n0 + wn + j * 16 + fr;          // h index (C/D col = lane&15)
        float bias = b1[e * HE + nn];
        #pragma unroll
        for (int i = 0; i < 4; i++) {
            #pragma unroll
            for (int r = 0; r < 4; r++) {
                int mm = wm + i * 16 + fq * 4 + r;  // C/D row = quad*4+reg
                if (m0 + mm < cn) {
                    float v = acc[i][j][r] + bias;
                    hbuf[(size_t)(base + m0 + mm) * HE + nn] = f2bf(gelu_exact(v));
                }
            }
        }
    }
}

// -------- GEMM2: ybuf[slot] = w_tok * (h @ w2[e] + b2[e])  (bf16, no atomics) --------
__global__ __launch_bounds__(256, 2) void gemm2_kernel(
        const unsigned short* __restrict__ hbuf,    // [NPAIR][HE] bf16
        const unsigned short* __restrict__ w2t,     // [E][DM][HE] bf16 (B^T layout)
        const float* __restrict__ b2,               // [E][DM]
        const int* __restrict__ pair_tok,
        const float* __restrict__ w_tok,
        const int* __restrict__ cnt, const int* __restrict__ offs,
        unsigned short* __restrict__ ybuf) {        // [NPAIR][DM] bf16
    int e = blockIdx.z;
    int cn = cnt[e];
    int m0 = blockIdx.y * BM;
    if (m0 >= cn) return;
    int n0 = blockIdx.x * BN;
    int base = offs[e];

    __shared__ __align__(16) unsigned short As[BM * LDT];
    __shared__ __align__(16) unsigned short Bs[BN * LDT];
    __shared__ float wts[BM];

    int tid = threadIdx.x;
    if (tid < BM) {
        int r = m0 + tid;
        int rr = (r < cn ? r : cn - 1);
        wts[tid] = w_tok[pair_tok[base + rr]];
    }

    const unsigned short* wB = w2t + (size_t)e * (DM * HE) + (size_t)n0 * HE;
    const unsigned short* aB = hbuf + (size_t)(base + m0) * HE;

    int lane = tid & 63;
    int wave = tid >> 6;
    int wm = (wave & 1) * 64;
    int wn = (wave >> 1) * 64;
    int fr = lane & 15;
    int fq = lane >> 4;

    f32x4 acc[4][4];
    #pragma unroll
    for (int i = 0; i < 4; i++)
        #pragma unroll
        for (int j = 0; j < 4; j++)
            acc[i][j] = (f32x4){0.f, 0.f, 0.f, 0.f};

    int lr = tid >> 3;
    int lc = (tid & 7) * 8;

    for (int k0 = 0; k0 < HE; k0 += BK) {
        __syncthreads();
        #pragma unroll
        for (int p = 0; p < 4; p++) {
            int r = lr + p * 32;
            int ar = (m0 + r < cn) ? r : 0;
            *(uint4*)(&As[r * LDT + lc]) = *(const uint4*)(&aB[(size_t)ar * HE + k0 + lc]);
            *(uint4*)(&Bs[r * LDT + lc]) = *(const uint4*)(&wB[(size_t)r * HE + k0 + lc]);
        }
        __syncthreads();
        #pragma unroll
        for (int kk = 0; kk < BK; kk += 32) {
            bf16x8 af[4], bfv[4];
            #pragma unroll
            for (int i = 0; i < 4; i++)
                af[i] = *(const bf16x8*)(&As[(wm + i * 16 + fr) * LDT + kk + fq * 8]);
            #pragma unroll
            for (int j = 0; j < 4; j++)
                bfv[j] = *(const bf16x8*)(&Bs[(wn + j * 16 + fr) * LDT + kk + fq * 8]);
            #pragma unroll
            for (int i = 0; i < 4; i++)
                #pragma unroll
                for (int j = 0; j < 4; j++)
                    acc[i][j] = __builtin_amdgcn_mfma_f32_16x16x32_bf16(af[i], bfv[j], acc[i][j], 0, 0, 0);
        }
    }

    #pragma unroll
    for (int j = 0; j < 4; j++) {
        int dd = n0 + wn + j * 16 + fr;           // output-dim col
        float bias = b2[e * DM + dd];
        #pragma unroll
        for (int i = 0; i < 4; i++) {
            #pragma unroll
            for (int r = 0; r < 4; r++) {
                int mm = wm + i * 16 + fq * 4 + r;
                if (m0 + mm < cn) {
                    float w = wts[mm];
                    ybuf[(size_t)(base + m0 + mm) * DM + dd] = f2bf(w * (acc[i][j][r] + bias));
                }
            }
        }
    }
}

// ---------------- combine: out[n] = yb[slot1] + yb[slot2] ----------------
__global__ void combine_kernel(const unsigned short* __restrict__ yb,
                               const int* __restrict__ slotmap,
                               float* __restrict__ out) {
    int i = blockIdx.x * 256 + threadIdx.x;   // over N_TOK * DM/4 groups
    int n = i >> 8;                            // DM/4 = 256 float4-groups per token
    int c = (i & 255) * 4;
    int s1 = slotmap[2 * n];
    int s2 = slotmap[2 * n + 1];
    ushort4 a = *(const ushort4*)(&yb[(size_t)s1 * DM + c]);
    ushort4 b = *(const ushort4*)(&yb[(size_t)s2 * DM + c]);
    float4 o;
    o.x = bf2f(a.x) + bf2f(b.x);
    o.y = bf2f(a.y) + bf2f(b.y);
    o.z = bf2f(a.z) + bf2f(b.z);
    o.w = bf2f(a.w) + bf2f(b.w);
    ((float4*)out)[i] = o;
}

extern "C" void kernel_launch(void* const* d_in, const int* in_sizes, int n_in,
                              void* d_out, int out_size, void* d_ws, size_t ws_size,
                              hipStream_t stream) {
    const float* x  = (const float*)d_in[0];
    const float* gw = (const float*)d_in[1];
    const float* w1 = (const float*)d_in[2];
    const float* b1 = (const float*)d_in[3];
    const float* w2 = (const float*)d_in[4];
    const float* b2 = (const float*)d_in[5];
    float* out = (float*)d_out;

    char* ws = (char*)d_ws;
    // ws layout (bytes), total ~59 MB.
    // ybuf (33.5 MB) overlays xb + w1t: both are dead by the time gemm2 runs.
    unsigned short* ybuf = (unsigned short*)(ws);              // 33,554,432 [NPAIR][DM] bf16
    unsigned short* xb   = (unsigned short*)(ws);              // 16,777,216 (dead after gemm1)
    unsigned short* w1t  = (unsigned short*)(ws + 16777216);   //  8,388,608 (dead after gemm1)
    unsigned short* w2t  = (unsigned short*)(ws + 33554432);   //  8,388,608  [e][d][h]
    unsigned short* hbuf = (unsigned short*)(ws + 41943040);   // 16,777,216  [NPAIR][HE]
    float* w_tok         = (float*)(ws + 58720256);            //     32,768
    int*   e_sel         = (int*)(ws + 58753024);              //     65,536
    int*   slotmap       = (int*)(ws + 58818560);              //     65,536
    int*   cnt           = (int*)(ws + 58884096);              //         32
    int*   offs          = (int*)(ws + 58884128);              //         32
    int*   cursor        = (int*)(ws + 58884160);              //         32
    int*   pair_tok      = (int*)(ws + 58884224);              //     65,536

    hipMemsetAsync(cnt, 0, 32, stream);

    cast_x_kernel<<<8192, 256, 0, stream>>>(x, xb);
    transpose_cast_kernel<<<dim3(HE / 64, DM / 64, NE), 256, 0, stream>>>(w1, w1t, DM, HE);
    transpose_cast_kernel<<<dim3(DM / 64, HE / 64, NE), 256, 0, stream>>>(w2, w2t, HE, DM);
    gate_kernel<<<N_TOK / 4, 256, 0, stream>>>(x, gw, w_tok, e_sel, cnt);
    scan_kernel<<<1, 64, 0, stream>>>(cnt, offs, cursor);
    scatter_kernel<<<N_TOK / 256, 256, 0, stream>>>(e_sel, offs, cursor, pair_tok, slotmap);
    gemm1_kernel<<<dim3(HE / BN, N_TOK / BM, NE), 256, 0, stream>>>(
        xb, w1t, b1, pair_tok, cnt, offs, hbuf);
    gemm2_kernel<<<dim3(DM / BN, N_TOK / BM, NE), 256, 0, stream>>>(
        hbuf, w2t, b2, pair_tok, w_tok, cnt, offs, ybuf);
    combine_kernel<<<(N_TOK * DM / 4) / 256, 256, 0, stream>>>(ybuf, slotmap, out);
}

// Round 3
// 319.703 us; speedup vs baseline: 1.8765x; 1.7301x over previous
//
#include <hip/hip_runtime.h>
#include <math.h>

#define N_TOK 8192
#define DM 1024
#define NE 8
#define HE 512
#define NPAIR 16384
#define HBLK 32     // histogram/scatter blocks (512 selection-entries each)

#define BM 128
#define BN 128
#define BK 64
#define LDT 72   // padded LDS row stride (elems): 144B -> breaks 16-way bank aliasing

#define GSTR 1028  // gate LDS row stride (fp32 elems)

typedef __bf16 bf16x8 __attribute__((ext_vector_type(8)));
typedef float f32x4 __attribute__((ext_vector_type(4)));

__device__ __forceinline__ unsigned short f2bf(float f) {
    unsigned int u = __float_as_uint(f);
    u += 0x7fffu + ((u >> 16) & 1u);   // RNE; inputs finite
    return (unsigned short)(u >> 16);
}

__device__ __forceinline__ float bf2f(unsigned short u) {
    return __uint_as_float(((unsigned int)u) << 16);
}

__device__ __forceinline__ float gelu_exact(float v) {
    return 0.5f * v * (1.0f + erff(v * 0.70710678118654752440f));
}

__device__ __forceinline__ double shfl_xor_dbl(double v, int m) {
    long long l = __double_as_longlong(v);
    int lo = (int)(l & 0xffffffffll);
    int hi = (int)(l >> 32);
    lo = __shfl_xor(lo, m, 64);
    hi = __shfl_xor(hi, m, 64);
    return __longlong_as_double(((long long)hi << 32) | (unsigned long long)(unsigned int)lo);
}

// ---------------- cast x fp32 -> bf16 ----------------
__global__ void cast_x_kernel(const float* __restrict__ x, unsigned short* __restrict__ xb) {
    int i = blockIdx.x * 256 + threadIdx.x;
    float4 v = ((const float4*)x)[i];
    ushort4 o;
    o.x = f2bf(v.x); o.y = f2bf(v.y); o.z = f2bf(v.z); o.w = f2bf(v.w);
    ((ushort4*)xb)[i] = o;
}

// ------- per-expert transpose+cast: src fp32 [R][C] -> dst bf16 [C][R] -------
__global__ void transpose_cast_kernel(const float* __restrict__ src,
                                      unsigned short* __restrict__ dst,
                                      int R, int C) {
    __shared__ float tile[64][65];
    const float* s = src + (size_t)blockIdx.z * R * C;
    unsigned short* d = dst + (size_t)blockIdx.z * R * C;
    int c0 = blockIdx.x * 64, r0 = blockIdx.y * 64;
    int tc = threadIdx.x & 63, tg = threadIdx.x >> 6;
    #pragma unroll
    for (int i = 0; i < 16; i++) {
        int r = tg * 16 + i;
        tile[r][tc] = s[(size_t)(r0 + r) * C + (c0 + tc)];
    }
    __syncthreads();
    #pragma unroll
    for (int i = 0; i < 16; i++) {
        int r = tg * 16 + i;
        d[(size_t)(c0 + r) * R + (r0 + tc)] = f2bf(tile[tc][r]);
    }
}

// ---------------- gating: softmax + top2 (double precision acc), NO atomics ----------------
__global__ __launch_bounds__(256) void gate_kernel(
        const float* __restrict__ x, const float* __restrict__ gw,
        float* __restrict__ w_tok, int* __restrict__ e_sel) {
    __shared__ float gls[NE * GSTR];
    int tid = threadIdx.x;
    for (int v = tid; v < 2048; v += 256) {
        float4 g4 = ((const float4*)gw)[v];
        int idx = v * 4;
        int d = idx >> 3;
        int e0 = idx & 7;   // 0 or 4
        gls[(e0    ) * GSTR + d] = g4.x;
        gls[(e0 + 1) * GSTR + d] = g4.y;
        gls[(e0 + 2) * GSTR + d] = g4.z;
        gls[(e0 + 3) * GSTR + d] = g4.w;
    }
    __syncthreads();

    int n = blockIdx.x * 4 + (tid >> 6);
    int lane = tid & 63;
    const float4* xr = (const float4*)(x + (size_t)n * DM);

    double s[NE];
    #pragma unroll
    for (int e = 0; e < NE; e++) s[e] = 0.0;

    #pragma unroll
    for (int i = 0; i < 4; i++) {
        float4 x4 = xr[i * 64 + lane];
        int d = (i * 64 + lane) * 4;
        #pragma unroll
        for (int e = 0; e < NE; e++) {
            float4 g4 = *(const float4*)(&gls[e * GSTR + d]);
            s[e] += (double)x4.x * (double)g4.x + (double)x4.y * (double)g4.y
                  + (double)x4.z * (double)g4.z + (double)x4.w * (double)g4.w;
        }
    }
    #pragma unroll
    for (int e = 0; e < NE; e++) {
        for (int off = 32; off > 0; off >>= 1)
            s[e] += shfl_xor_dbl(s[e], off);
    }
    if (lane == 0) {
        double m = s[0];
        for (int e = 1; e < NE; e++) if (s[e] > m) m = s[e];
        double sum = 0.0;
        for (int e = 0; e < NE; e++) sum += exp(s[e] - m);
        int i1 = 0; double v1 = s[0];
        for (int e = 1; e < NE; e++) if (s[e] > v1) { v1 = s[e]; i1 = e; }
        int i2 = -1; double v2 = -1e300;
        for (int e = 0; e < NE; e++) if (e != i1 && s[e] > v2) { v2 = s[e]; i2 = e; }
        w_tok[n] = (float)((exp(v1 - m) + exp(v2 - m)) / sum);
        e_sel[2 * n]     = i1;
        e_sel[2 * n + 1] = i2;
    }
}

// ------- per-block histogram over selection entries (LDS atomics only) -------
__global__ void hist_kernel(const int* __restrict__ e_sel, int* __restrict__ blockhist) {
    __shared__ int h[NE];
    int tid = threadIdx.x;
    if (tid < NE) h[tid] = 0;
    __syncthreads();
    int base = blockIdx.x * 512;
    atomicAdd(&h[e_sel[base + tid]], 1);
    atomicAdd(&h[e_sel[base + 256 + tid]], 1);
    __syncthreads();
    if (tid < NE) blockhist[blockIdx.x * NE + tid] = h[tid];
}

// ------- scan: cnt[e], offs[e], per-block start bstart[b][e] (trivial sizes) -------
__global__ void scan_kernel(const int* __restrict__ blockhist, int* __restrict__ cnt,
                            int* __restrict__ offs, int* __restrict__ bstart) {
    if (threadIdx.x == 0) {
        int tot[NE];
        for (int e = 0; e < NE; e++) {
            int t = 0;
            for (int b = 0; b < HBLK; b++) t += blockhist[b * NE + e];
            tot[e] = t;
            cnt[e] = t;
        }
        int a = 0;
        for (int e = 0; e < NE; e++) { offs[e] = a; a += tot[e]; }
        for (int e = 0; e < NE; e++) {
            int r = offs[e];
            for (int b = 0; b < HBLK; b++) {
                bstart[b * NE + e] = r;
                r += blockhist[b * NE + e];
            }
        }
    }
}

// ------- scatter: slot via LDS counter seeded from bstart (no global atomics) -------
__global__ void scatter_kernel(const int* __restrict__ e_sel, const int* __restrict__ bstart,
                               int* __restrict__ pair_tok, int* __restrict__ slotmap) {
    __shared__ int pos[NE];
    int tid = threadIdx.x;
    if (tid < NE) pos[tid] = bstart[blockIdx.x * NE + tid];
    __syncthreads();
    int base = blockIdx.x * 512;
    #pragma unroll
    for (int k = 0; k < 2; k++) {
        int i = base + k * 256 + tid;
        int e = e_sel[i];
        int slot = atomicAdd(&pos[e], 1);
        pair_tok[slot] = i >> 1;
        slotmap[i] = slot;
    }
}

// ---------------- GEMM1: h = gelu(x_gathered @ w1[e] + b1[e]) ----------------
__global__ __launch_bounds__(256, 2) void gemm1_kernel(
        const unsigned short* __restrict__ xb,      // [N_TOK][DM] bf16
        const unsigned short* __restrict__ w1t,     // [E][HE][DM] bf16 (B^T layout)
        const float* __restrict__ b1,               // [E][HE]
        const int* __restrict__ pair_tok,
        const int* __restrict__ cnt, const int* __restrict__ offs,
        unsigned short* __restrict__ hbuf) {        // [NPAIR][HE] bf16
    int e = blockIdx.z;
    int cn = cnt[e];
    int m0 = blockIdx.y * BM;
    if (m0 >= cn) return;
    int n0 = blockIdx.x * BN;
    int base = offs[e];

    __shared__ __align__(16) unsigned short As[BM * LDT];
    __shared__ __align__(16) unsigned short Bs[BN * LDT];
    __shared__ int tks[BM];

    int tid = threadIdx.x;
    if (tid < BM) {
        int r = m0 + tid;
        tks[tid] = pair_tok[base + (r < cn ? r : 0)];
    }

    const unsigned short* wB = w1t + (size_t)e * (HE * DM) + (size_t)n0 * DM;

    int lane = tid & 63;
    int wave = tid >> 6;
    int wm = (wave & 1) * 64;
    int wn = (wave >> 1) * 64;
    int fr = lane & 15;
    int fq = lane >> 4;

    f32x4 acc[4][4];
    #pragma unroll
    for (int i = 0; i < 4; i++)
        #pragma unroll
        for (int j = 0; j < 4; j++)
            acc[i][j] = (f32x4){0.f, 0.f, 0.f, 0.f};

    int lr = tid >> 3;
    int lc = (tid & 7) * 8;

    for (int k0 = 0; k0 < DM; k0 += BK) {
        __syncthreads();
        #pragma unroll
        for (int p = 0; p < 4; p++) {
            int r = lr + p * 32;
            int t = tks[r];
            *(uint4*)(&As[r * LDT + lc]) = *(const uint4*)(&xb[(size_t)t * DM + k0 + lc]);
            *(uint4*)(&Bs[r * LDT + lc]) = *(const uint4*)(&wB[(size_t)r * DM + k0 + lc]);
        }
        __syncthreads();
        #pragma unroll
        for (int kk = 0; kk < BK; kk += 32) {
            bf16x8 af[4], bfv[4];
            #pragma unroll
            for (int i = 0; i < 4; i++)
                af[i] = *(const bf16x8*)(&As[(wm + i * 16 + fr) * LDT + kk + fq * 8]);
            #pragma unroll
            for (int j = 0; j < 4; j++)
                bfv[j] = *(const bf16x8*)(&Bs[(wn + j * 16 + fr) * LDT + kk + fq * 8]);
            #pragma unroll
            for (int i = 0; i < 4; i++)
                #pragma unroll
                for (int j = 0; j < 4; j++)
                    acc[i][j] = __builtin_amdgcn_mfma_f32_16x16x32_bf16(af[i], bfv[j], acc[i][j], 0, 0, 0);
        }
    }

    #pragma unroll
    for (int j = 0; j < 4; j++) {
        int nn = n0 + wn + j * 16 + fr;          // h index (C/D col = lane&15)
        float bias = b1[e * HE + nn];
        #pragma unroll
        for (int i = 0; i < 4; i++) {
            #pragma unroll
            for (int r = 0; r < 4; r++) {
                int mm = wm + i * 16 + fq * 4 + r;  // C/D row = quad*4+reg
                if (m0 + mm < cn) {
                    float v = acc[i][j][r] + bias;
                    hbuf[(size_t)(base + m0 + mm) * HE + nn] = f2bf(gelu_exact(v));
                }
            }
        }
    }
}

// -------- GEMM2: ybuf[slot] = w_tok * (h @ w2[e] + b2[e])  (bf16, no atomics) --------
__global__ __launch_bounds__(256, 2) void gemm2_kernel(
        const unsigned short* __restrict__ hbuf,    // [NPAIR][HE] bf16
        const unsigned short* __restrict__ w2t,     // [E][DM][HE] bf16 (B^T layout)
        const float* __restrict__ b2,               // [E][DM]
        const int* __restrict__ pair_tok,
        const float* __restrict__ w_tok,
        const int* __restrict__ cnt, const int* __restrict__ offs,
        unsigned short* __restrict__ ybuf) {        // [NPAIR][DM] bf16
    int e = blockIdx.z;
    int cn = cnt[e];
    int m0 = blockIdx.y * BM;
    if (m0 >= cn) return;
    int n0 = blockIdx.x * BN;
    int base = offs[e];

    __shared__ __align__(16) unsigned short As[BM * LDT];
    __shared__ __align__(16) unsigned short Bs[BN * LDT];
    __shared__ float wts[BM];

    int tid = threadIdx.x;
    if (tid < BM) {
        int r = m0 + tid;
        int rr = (r < cn ? r : cn - 1);
        wts[tid] = w_tok[pair_tok[base + rr]];
    }

    const unsigned short* wB = w2t + (size_t)e * (DM * HE) + (size_t)n0 * HE;
    const unsigned short* aB = hbuf + (size_t)(base + m0) * HE;

    int lane = tid & 63;
    int wave = tid >> 6;
    int wm = (wave & 1) * 64;
    int wn = (wave >> 1) * 64;
    int fr = lane & 15;
    int fq = lane >> 4;

    f32x4 acc[4][4];
    #pragma unroll
    for (int i = 0; i < 4; i++)
        #pragma unroll
        for (int j = 0; j < 4; j++)
            acc[i][j] = (f32x4){0.f, 0.f, 0.f, 0.f};

    int lr = tid >> 3;
    int lc = (tid & 7) * 8;

    for (int k0 = 0; k0 < HE; k0 += BK) {
        __syncthreads();
        #pragma unroll
        for (int p = 0; p < 4; p++) {
            int r = lr + p * 32;
            int ar = (m0 + r < cn) ? r : 0;
            *(uint4*)(&As[r * LDT + lc]) = *(const uint4*)(&aB[(size_t)ar * HE + k0 + lc]);
            *(uint4*)(&Bs[r * LDT + lc]) = *(const uint4*)(&wB[(size_t)r * HE + k0 + lc]);
        }
        __syncthreads();
        #pragma unroll
        for (int kk = 0; kk < BK; kk += 32) {
            bf16x8 af[4], bfv[4];
            #pragma unroll
            for (int i = 0; i < 4; i++)
                af[i] = *(const bf16x8*)(&As[(wm + i * 16 + fr) * LDT + kk + fq * 8]);
            #pragma unroll
            for (int j = 0; j < 4; j++)
                bfv[j] = *(const bf16x8*)(&Bs[(wn + j * 16 + fr) * LDT + kk + fq * 8]);
            #pragma unroll
            for (int i = 0; i < 4; i++)
                #pragma unroll
                for (int j = 0; j < 4; j++)
                    acc[i][j] = __builtin_amdgcn_mfma_f32_16x16x32_bf16(af[i], bfv[j], acc[i][j], 0, 0, 0);
        }
    }

    #pragma unroll
    for (int j = 0; j < 4; j++) {
        int dd = n0 + wn + j * 16 + fr;           // output-dim col
        float bias = b2[e * DM + dd];
        #pragma unroll
        for (int i = 0; i < 4; i++) {
            #pragma unroll
            for (int r = 0; r < 4; r++) {
                int mm = wm + i * 16 + fq * 4 + r;
                if (m0 + mm < cn) {
                    float w = wts[mm];
                    ybuf[(size_t)(base + m0 + mm) * DM + dd] = f2bf(w * (acc[i][j][r] + bias));
                }
            }
        }
    }
}

// ---------------- combine: out[n] = yb[slot1] + yb[slot2] ----------------
__global__ void combine_kernel(const unsigned short* __restrict__ yb,
                               const int* __restrict__ slotmap,
                               float* __restrict__ out) {
    int i = blockIdx.x * 256 + threadIdx.x;
    int n = i >> 8;
    int c = (i & 255) * 4;
    int s1 = slotmap[2 * n];
    int s2 = slotmap[2 * n + 1];
    ushort4 a = *(const ushort4*)(&yb[(size_t)s1 * DM + c]);
    ushort4 b = *(const ushort4*)(&yb[(size_t)s2 * DM + c]);
    float4 o;
    o.x = bf2f(a.x) + bf2f(b.x);
    o.y = bf2f(a.y) + bf2f(b.y);
    o.z = bf2f(a.z) + bf2f(b.z);
    o.w = bf2f(a.w) + bf2f(b.w);
    ((float4*)out)[i] = o;
}

extern "C" void kernel_launch(void* const* d_in, const int* in_sizes, int n_in,
                              void* d_out, int out_size, void* d_ws, size_t ws_size,
                              hipStream_t stream) {
    const float* x  = (const float*)d_in[0];
    const float* gw = (const float*)d_in[1];
    const float* w1 = (const float*)d_in[2];
    const float* b1 = (const float*)d_in[3];
    const float* w2 = (const float*)d_in[4];
    const float* b2 = (const float*)d_in[5];
    float* out = (float*)d_out;

    char* ws = (char*)d_ws;
    // ws layout (bytes), total ~59 MB.
    // ybuf (33.5 MB) overlays xb + w1t: both dead by the time gemm2 runs.
    unsigned short* ybuf = (unsigned short*)(ws);              // 33,554,432 [NPAIR][DM] bf16
    unsigned short* xb   = (unsigned short*)(ws);              // 16,777,216 (dead after gemm1)
    unsigned short* w1t  = (unsigned short*)(ws + 16777216);   //  8,388,608 (dead after gemm1)
    unsigned short* w2t  = (unsigned short*)(ws + 33554432);   //  8,388,608  [e][d][h]
    unsigned short* hbuf = (unsigned short*)(ws + 41943040);   // 16,777,216  [NPAIR][HE]
    float* w_tok         = (float*)(ws + 58720256);            //     32,768
    int*   e_sel         = (int*)(ws + 58753024);              //     65,536
    int*   slotmap       = (int*)(ws + 58818560);              //     65,536
    int*   cnt           = (int*)(ws + 58884096);              //         32
    int*   offs          = (int*)(ws + 58884128);              //         32
    int*   pair_tok      = (int*)(ws + 58884224);              //     65,536
    int*   blockhist     = (int*)(ws + 58949760);              //      1,024
    int*   bstart        = (int*)(ws + 58950784);              //      1,024

    cast_x_kernel<<<8192, 256, 0, stream>>>(x, xb);
    transpose_cast_kernel<<<dim3(HE / 64, DM / 64, NE), 256, 0, stream>>>(w1, w1t, DM, HE);
    transpose_cast_kernel<<<dim3(DM / 64, HE / 64, NE), 256, 0, stream>>>(w2, w2t, HE, DM);
    gate_kernel<<<N_TOK / 4, 256, 0, stream>>>(x, gw, w_tok, e_sel);
    hist_kernel<<<HBLK, 256, 0, stream>>>(e_sel, blockhist);
    scan_kernel<<<1, 64, 0, stream>>>(blockhist, cnt, offs, bstart);
    scatter_kernel<<<HBLK, 256, 0, stream>>>(e_sel, bstart, pair_tok, slotmap);
    gemm1_kernel<<<dim3(HE / BN, N_TOK / BM, NE), 256, 0, stream>>>(
        xb, w1t, b1, pair_tok, cnt, offs, hbuf);
    gemm2_kernel<<<dim3(DM / BN, N_TOK / BM, NE), 256, 0, stream>>>(
        hbuf, w2t, b2, pair_tok, w_tok, cnt, offs, ybuf);
    combine_kernel<<<(N_TOK * DM / 4) / 256, 256, 0, stream>>>(ybuf, slotmap, out);
}

// Round 4
// 261.966 us; speedup vs baseline: 2.2901x; 1.2204x over previous
//
#include <hip/hip_runtime.h>
#include <math.h>

#define N_TOK 8192
#define DM 1024
#define NE 8
#define HE 512
#define NPAIR 16384

#define BM 128
#define BN 128
#define BK 64          // 64 bf16 = 128 B per LDS row, unpadded (global_load_lds needs contiguity)

#define GSTR 1028      // gate LDS row stride (fp32 elems)

typedef __bf16 bf16x8 __attribute__((ext_vector_type(8)));
typedef float f32x4 __attribute__((ext_vector_type(4)));

#define GLOBAL_AS __attribute__((address_space(1)))
#define LDS_AS    __attribute__((address_space(3)))

// async global -> LDS, 16 B per lane. LDS dest must be wave-uniform base; data
// lands at base + lane*16. We pick which global bytes go to which lane (XOR
// swizzle on the SOURCE address) since the LDS side is rigid.
__device__ __forceinline__ void gl_lds16(const void* g, void* lds) {
    __builtin_amdgcn_global_load_lds((const GLOBAL_AS unsigned int*)g,
                                     (LDS_AS unsigned int*)lds, 16, 0, 0);
}

__device__ __forceinline__ unsigned short f2bf(float f) {
    unsigned int u = __float_as_uint(f);
    u += 0x7fffu + ((u >> 16) & 1u);   // RNE; inputs finite
    return (unsigned short)(u >> 16);
}

__device__ __forceinline__ float bf2f(unsigned short u) {
    return __uint_as_float(((unsigned int)u) << 16);
}

__device__ __forceinline__ float gelu_exact(float v) {
    return 0.5f * v * (1.0f + erff(v * 0.70710678118654752440f));
}

__device__ __forceinline__ double shfl_xor_dbl(double v, int m) {
    long long l = __double_as_longlong(v);
    int lo = (int)(l & 0xffffffffll);
    int hi = (int)(l >> 32);
    lo = __shfl_xor(lo, m, 64);
    hi = __shfl_xor(hi, m, 64);
    return __longlong_as_double(((long long)hi << 32) | (unsigned long long)(unsigned int)lo);
}

// ---------------- cast x fp32 -> bf16 ----------------
__global__ void cast_x_kernel(const float* __restrict__ x, unsigned short* __restrict__ xb) {
    int i = blockIdx.x * 256 + threadIdx.x;
    float4 v = ((const float4*)x)[i];
    ushort4 o;
    o.x = f2bf(v.x); o.y = f2bf(v.y); o.z = f2bf(v.z); o.w = f2bf(v.w);
    ((ushort4*)xb)[i] = o;
}

// ------- per-expert transpose+cast: src fp32 [R][C] -> dst bf16 [C][R] -------
__global__ void transpose_cast_kernel(const float* __restrict__ src,
                                      unsigned short* __restrict__ dst,
                                      int R, int C) {
    __shared__ float tile[64][65];
    const float* s = src + (size_t)blockIdx.z * R * C;
    unsigned short* d = dst + (size_t)blockIdx.z * R * C;
    int c0 = blockIdx.x * 64, r0 = blockIdx.y * 64;
    int tc = threadIdx.x & 63, tg = threadIdx.x >> 6;
    #pragma unroll
    for (int i = 0; i < 16; i++) {
        int r = tg * 16 + i;
        tile[r][tc] = s[(size_t)(r0 + r) * C + (c0 + tc)];
    }
    __syncthreads();
    #pragma unroll
    for (int i = 0; i < 16; i++) {
        int r = tg * 16 + i;
        d[(size_t)(c0 + r) * R + (r0 + tc)] = f2bf(tile[tc][r]);
    }
}

// ---------------- gating: softmax + top2 (double precision acc), NO atomics ----------------
__global__ __launch_bounds__(256) void gate_kernel(
        const float* __restrict__ x, const float* __restrict__ gw,
        float* __restrict__ w_tok, int* __restrict__ e_sel) {
    __shared__ float gls[NE * GSTR];
    int tid = threadIdx.x;
    for (int v = tid; v < 2048; v += 256) {
        float4 g4 = ((const float4*)gw)[v];
        int idx = v * 4;
        int d = idx >> 3;
        int e0 = idx & 7;   // 0 or 4
        gls[(e0    ) * GSTR + d] = g4.x;
        gls[(e0 + 1) * GSTR + d] = g4.y;
        gls[(e0 + 2) * GSTR + d] = g4.z;
        gls[(e0 + 3) * GSTR + d] = g4.w;
    }
    __syncthreads();

    int n = blockIdx.x * 4 + (tid >> 6);
    int lane = tid & 63;
    const float4* xr = (const float4*)(x + (size_t)n * DM);

    double s[NE];
    #pragma unroll
    for (int e = 0; e < NE; e++) s[e] = 0.0;

    #pragma unroll
    for (int i = 0; i < 4; i++) {
        float4 x4 = xr[i * 64 + lane];
        int d = (i * 64 + lane) * 4;
        #pragma unroll
        for (int e = 0; e < NE; e++) {
            float4 g4 = *(const float4*)(&gls[e * GSTR + d]);
            s[e] += (double)x4.x * (double)g4.x + (double)x4.y * (double)g4.y
                  + (double)x4.z * (double)g4.z + (double)x4.w * (double)g4.w;
        }
    }
    #pragma unroll
    for (int e = 0; e < NE; e++) {
        for (int off = 32; off > 0; off >>= 1)
            s[e] += shfl_xor_dbl(s[e], off);
    }
    if (lane == 0) {
        double m = s[0];
        for (int e = 1; e < NE; e++) if (s[e] > m) m = s[e];
        double sum = 0.0;
        for (int e = 0; e < NE; e++) sum += exp(s[e] - m);
        int i1 = 0; double v1 = s[0];
        for (int e = 1; e < NE; e++) if (s[e] > v1) { v1 = s[e]; i1 = e; }
        int i2 = -1; double v2 = -1e300;
        for (int e = 0; e < NE; e++) if (e != i1 && s[e] > v2) { v2 = s[e]; i2 = e; }
        w_tok[n] = (float)((exp(v1 - m) + exp(v2 - m)) / sum);
        e_sel[2 * n]     = i1;
        e_sel[2 * n + 1] = i2;
    }
}

// ------ routing: histogram + scan + scatter, ONE block, all in LDS ------
__global__ __launch_bounds__(1024) void route_kernel(
        const int* __restrict__ e_sel, int* __restrict__ cnt, int* __restrict__ offs,
        int* __restrict__ pair_tok, int* __restrict__ slotmap) {
    __shared__ int wbin[16][NE];     // per-wave bins -> later per-wave cursors
    __shared__ int wstart[16][NE];
    int tid = threadIdx.x;
    int w = tid >> 6, l = tid & 63;
    if (l < NE) wbin[w][l] = 0;
    __syncthreads();

    int sel[16];
    #pragma unroll
    for (int k = 0; k < 16; k++) {
        sel[k] = e_sel[tid * 16 + k];
        atomicAdd(&wbin[w][sel[k]], 1);
    }
    __syncthreads();

    if (tid == 0) {   // 128 LDS values: trivial serial scan
        int a = 0;
        for (int e = 0; e < NE; e++) {
            int t = 0;
            for (int ww = 0; ww < 16; ww++) t += wbin[ww][e];
            cnt[e] = t; offs[e] = a;
            int r = a;
            for (int ww = 0; ww < 16; ww++) { wstart[ww][e] = r; r += wbin[ww][e]; }
            a += t;
        }
    }
    __syncthreads();
    if (l < NE) wbin[w][l] = wstart[w][l];   // reuse as cursors
    __syncthreads();

    #pragma unroll
    for (int k = 0; k < 16; k++) {
        int i = tid * 16 + k;
        int slot = atomicAdd(&wbin[w][sel[k]], 1);
        pair_tok[slot] = i >> 1;
        slotmap[i] = slot;
    }
}

// ---------------- GEMM1: h = gelu(x_gathered @ w1[e] + b1[e]) ----------------
// LDS: unpadded [128][64] bf16 tiles, filled by global_load_lds with XOR source
// swizzle: data for k-group g of row r sits at group g^(r&7).
__global__ __launch_bounds__(256, 2) void gemm1_kernel(
        const unsigned short* __restrict__ xb,      // [N_TOK][DM] bf16
        const unsigned short* __restrict__ w1t,     // [E][HE][DM] bf16 (B^T layout)
        const float* __restrict__ b1,               // [E][HE]
        const int* __restrict__ pair_tok,
        const int* __restrict__ cnt, const int* __restrict__ offs,
        unsigned short* __restrict__ hbuf) {        // [NPAIR][HE] bf16
    int e = blockIdx.z;
    int cn = cnt[e];
    int m0 = blockIdx.y * BM;
    if (m0 >= cn) return;
    int n0 = blockIdx.x * BN;
    int base = offs[e];

    __shared__ __align__(16) unsigned short As[BM * BK];   // 16 KB
    __shared__ __align__(16) unsigned short Bs[BN * BK];   // 16 KB
    __shared__ int tks[BM];

    int tid = threadIdx.x;
    if (tid < BM) {
        int r = m0 + tid;
        tks[tid] = pair_tok[base + (r < cn ? r : 0)];
    }
    __syncthreads();

    int lane = tid & 63;
    int w = tid >> 6;
    int wu = __builtin_amdgcn_readfirstlane(w);
    int l3 = lane >> 3, l7 = lane & 7;
    int g = l7 ^ l3;               // swizzled source k-group for this lane

    // per-lane global source base addresses (row fixed over K-loop)
    const char* aptr[4];
    const char* bptr[4];
    #pragma unroll
    for (int j = 0; j < 4; j++) {
        int row = w * 32 + j * 8 + l3;
        aptr[j] = (const char*)xb  + (size_t)tks[row] * (DM * 2) + g * 16;
        bptr[j] = (const char*)w1t + ((size_t)e * HE + n0 + row) * (DM * 2) + g * 16;
    }

    int wm = (w & 1) * 64;
    int wn = (w >> 1) * 64;
    int fr = lane & 15;
    int fq = lane >> 4;

    f32x4 acc[4][4];
    #pragma unroll
    for (int i = 0; i < 4; i++)
        #pragma unroll
        for (int j = 0; j < 4; j++)
            acc[i][j] = (f32x4){0.f, 0.f, 0.f, 0.f};

    for (int k0 = 0; k0 < DM; k0 += BK) {
        int kb = k0 * 2;
        #pragma unroll
        for (int j = 0; j < 4; j++) {
            gl_lds16(aptr[j] + kb, (char*)As + wu * 4096 + j * 1024);
            gl_lds16(bptr[j] + kb, (char*)Bs + wu * 4096 + j * 1024);
        }
        __syncthreads();   // drains vmcnt: LDS tiles ready
        #pragma unroll
        for (int kk2 = 0; kk2 < 2; kk2++) {
            int sw = ((kk2 * 4 + fq) ^ (fr & 7)) << 4;   // swizzled byte group
            bf16x8 af[4], bfv[4];
            #pragma unroll
            for (int i = 0; i < 4; i++)
                af[i] = *(const bf16x8*)((const char*)As + (wm + i * 16 + fr) * 128 + sw);
            #pragma unroll
            for (int j = 0; j < 4; j++)
                bfv[j] = *(const bf16x8*)((const char*)Bs + (wn + j * 16 + fr) * 128 + sw);
            #pragma unroll
            for (int i = 0; i < 4; i++)
                #pragma unroll
                for (int j = 0; j < 4; j++)
                    acc[i][j] = __builtin_amdgcn_mfma_f32_16x16x32_bf16(af[i], bfv[j], acc[i][j], 0, 0, 0);
        }
        __syncthreads();   // all waves done reading before next stage overwrites
    }

    #pragma unroll
    for (int j = 0; j < 4; j++) {
        int nn = n0 + wn + j * 16 + fr;          // h index (C/D col = lane&15)
        float bias = b1[e * HE + nn];
        #pragma unroll
        for (int i = 0; i < 4; i++) {
            #pragma unroll
            for (int r = 0; r < 4; r++) {
                int mm = wm + i * 16 + fq * 4 + r;  // C/D row = quad*4+reg
                if (m0 + mm < cn) {
                    float v = acc[i][j][r] + bias;
                    hbuf[(size_t)(base + m0 + mm) * HE + nn] = f2bf(gelu_exact(v));
                }
            }
        }
    }
}

// -------- GEMM2: ybuf[slot] = w_tok * (h @ w2[e] + b2[e])  (bf16, no atomics) --------
__global__ __launch_bounds__(256, 2) void gemm2_kernel(
        const unsigned short* __restrict__ hbuf,    // [NPAIR][HE] bf16
        const unsigned short* __restrict__ w2t,     // [E][DM][HE] bf16 (B^T layout)
        const float* __restrict__ b2,               // [E][DM]
        const int* __restrict__ pair_tok,
        const float* __restrict__ w_tok,
        const int* __restrict__ cnt, const int* __restrict__ offs,
        unsigned short* __restrict__ ybuf) {        // [NPAIR][DM] bf16
    int e = blockIdx.z;
    int cn = cnt[e];
    int m0 = blockIdx.y * BM;
    if (m0 >= cn) return;
    int n0 = blockIdx.x * BN;
    int base = offs[e];

    __shared__ __align__(16) unsigned short As[BM * BK];
    __shared__ __align__(16) unsigned short Bs[BN * BK];
    __shared__ float wts[BM];

    int tid = threadIdx.x;
    if (tid < BM) {
        int r = m0 + tid;
        int rr = (r < cn ? r : cn - 1);
        wts[tid] = w_tok[pair_tok[base + rr]];
    }
    __syncthreads();

    int lane = tid & 63;
    int w = tid >> 6;
    int wu = __builtin_amdgcn_readfirstlane(w);
    int l3 = lane >> 3, l7 = lane & 7;
    int g = l7 ^ l3;

    const char* aptr[4];
    const char* bptr[4];
    #pragma unroll
    for (int j = 0; j < 4; j++) {
        int row = w * 32 + j * 8 + l3;
        int crow = (m0 + row < cn) ? row : 0;                       // clamp OOB rows
        aptr[j] = (const char*)hbuf + (size_t)(base + m0 + crow) * (HE * 2) + g * 16;
        bptr[j] = (const char*)w2t  + ((size_t)e * DM + n0 + row) * (HE * 2) + g * 16;
    }

    int wm = (w & 1) * 64;
    int wn = (w >> 1) * 64;
    int fr = lane & 15;
    int fq = lane >> 4;

    f32x4 acc[4][4];
    #pragma unroll
    for (int i = 0; i < 4; i++)
        #pragma unroll
        for (int j = 0; j < 4; j++)
            acc[i][j] = (f32x4){0.f, 0.f, 0.f, 0.f};

    for (int k0 = 0; k0 < HE; k0 += BK) {
        int kb = k0 * 2;
        #pragma unroll
        for (int j = 0; j < 4; j++) {
            gl_lds16(aptr[j] + kb, (char*)As + wu * 4096 + j * 1024);
            gl_lds16(bptr[j] + kb, (char*)Bs + wu * 4096 + j * 1024);
        }
        __syncthreads();
        #pragma unroll
        for (int kk2 = 0; kk2 < 2; kk2++) {
            int sw = ((kk2 * 4 + fq) ^ (fr & 7)) << 4;
            bf16x8 af[4], bfv[4];
            #pragma unroll
            for (int i = 0; i < 4; i++)
                af[i] = *(const bf16x8*)((const char*)As + (wm + i * 16 + fr) * 128 + sw);
            #pragma unroll
            for (int j = 0; j < 4; j++)
                bfv[j] = *(const bf16x8*)((const char*)Bs + (wn + j * 16 + fr) * 128 + sw);
            #pragma unroll
            for (int i = 0; i < 4; i++)
                #pragma unroll
                for (int j = 0; j < 4; j++)
                    acc[i][j] = __builtin_amdgcn_mfma_f32_16x16x32_bf16(af[i], bfv[j], acc[i][j], 0, 0, 0);
        }
        __syncthreads();
    }

    #pragma unroll
    for (int j = 0; j < 4; j++) {
        int dd = n0 + wn + j * 16 + fr;           // output-dim col
        float bias = b2[e * DM + dd];
        #pragma unroll
        for (int i = 0; i < 4; i++) {
            #pragma unroll
            for (int r = 0; r < 4; r++) {
                int mm = wm + i * 16 + fq * 4 + r;
                if (m0 + mm < cn) {
                    float wgt = wts[mm];
                    ybuf[(size_t)(base + m0 + mm) * DM + dd] = f2bf(wgt * (acc[i][j][r] + bias));
                }
            }
        }
    }
}

// ---------------- combine: out[n] = yb[slot1] + yb[slot2] ----------------
__global__ void combine_kernel(const unsigned short* __restrict__ yb,
                               const int* __restrict__ slotmap,
                               float* __restrict__ out) {
    int i = blockIdx.x * 256 + threadIdx.x;
    int n = i >> 8;
    int c = (i & 255) * 4;
    int s1 = slotmap[2 * n];
    int s2 = slotmap[2 * n + 1];
    ushort4 a = *(const ushort4*)(&yb[(size_t)s1 * DM + c]);
    ushort4 b = *(const ushort4*)(&yb[(size_t)s2 * DM + c]);
    float4 o;
    o.x = bf2f(a.x) + bf2f(b.x);
    o.y = bf2f(a.y) + bf2f(b.y);
    o.z = bf2f(a.z) + bf2f(b.z);
    o.w = bf2f(a.w) + bf2f(b.w);
    ((float4*)out)[i] = o;
}

extern "C" void kernel_launch(void* const* d_in, const int* in_sizes, int n_in,
                              void* d_out, int out_size, void* d_ws, size_t ws_size,
                              hipStream_t stream) {
    const float* x  = (const float*)d_in[0];
    const float* gw = (const float*)d_in[1];
    const float* w1 = (const float*)d_in[2];
    const float* b1 = (const float*)d_in[3];
    const float* w2 = (const float*)d_in[4];
    const float* b2 = (const float*)d_in[5];
    float* out = (float*)d_out;

    char* ws = (char*)d_ws;
    // ws layout (bytes), total ~59 MB.
    // ybuf (33.5 MB) overlays xb + w1t: both dead by the time gemm2 runs.
    unsigned short* ybuf = (unsigned short*)(ws);              // 33,554,432 [NPAIR][DM] bf16
    unsigned short* xb   = (unsigned short*)(ws);              // 16,777,216 (dead after gemm1)
    unsigned short* w1t  = (unsigned short*)(ws + 16777216);   //  8,388,608 (dead after gemm1)
    unsigned short* w2t  = (unsigned short*)(ws + 33554432);   //  8,388,608  [e][d][h]
    unsigned short* hbuf = (unsigned short*)(ws + 41943040);   // 16,777,216  [NPAIR][HE]
    float* w_tok         = (float*)(ws + 58720256);            //     32,768
    int*   e_sel         = (int*)(ws + 58753024);              //     65,536
    int*   slotmap       = (int*)(ws + 58818560);              //     65,536
    int*   cnt           = (int*)(ws + 58884096);              //         32
    int*   offs          = (int*)(ws + 58884128);              //         32
    int*   pair_tok      = (int*)(ws + 58884224);              //     65,536

    cast_x_kernel<<<8192, 256, 0, stream>>>(x, xb);
    transpose_cast_kernel<<<dim3(HE / 64, DM / 64, NE), 256, 0, stream>>>(w1, w1t, DM, HE);
    transpose_cast_kernel<<<dim3(DM / 64, HE / 64, NE), 256, 0, stream>>>(w2, w2t, HE, DM);
    gate_kernel<<<N_TOK / 4, 256, 0, stream>>>(x, gw, w_tok, e_sel);
    route_kernel<<<1, 1024, 0, stream>>>(e_sel, cnt, offs, pair_tok, slotmap);
    gemm1_kernel<<<dim3(HE / BN, N_TOK / BM, NE), 256, 0, stream>>>(
        xb, w1t, b1, pair_tok, cnt, offs, hbuf);
    gemm2_kernel<<<dim3(DM / BN, N_TOK / BM, NE), 256, 0, stream>>>(
        hbuf, w2t, b2, pair_tok, w_tok, cnt, offs, ybuf);
    combine_kernel<<<(N_TOK * DM / 4) / 256, 256, 0, stream>>>(ybuf, slotmap, out);
}

// Round 5
// 259.958 us; speedup vs baseline: 2.3078x; 1.0077x over previous
//
#include <hip/hip_runtime.h>
#include <math.h>

#define N_TOK 8192
#define DM 1024
#define NE 8
#define HE 512
#define NPAIR 16384

#define BM 128
#define BN 128
#define BK 64          // 64 bf16 = 128 B per LDS row, unpadded (global_load_lds contiguity)

#define GSTR 1028      // gate LDS row stride (fp32 elems)

typedef __bf16 bf16x8 __attribute__((ext_vector_type(8)));
typedef float f32x4 __attribute__((ext_vector_type(4)));

#define GLOBAL_AS __attribute__((address_space(1)))
#define LDS_AS    __attribute__((address_space(3)))

__device__ __forceinline__ void gl_lds16(const void* g, void* lds) {
    __builtin_amdgcn_global_load_lds((const GLOBAL_AS unsigned int*)g,
                                     (LDS_AS unsigned int*)lds, 16, 0, 0);
}

__device__ __forceinline__ unsigned short f2bf(float f) {
    unsigned int u = __float_as_uint(f);
    u += 0x7fffu + ((u >> 16) & 1u);   // RNE; inputs finite
    return (unsigned short)(u >> 16);
}

__device__ __forceinline__ float bf2f(unsigned short u) {
    return __uint_as_float(((unsigned int)u) << 16);
}

__device__ __forceinline__ float gelu_exact(float v) {
    return 0.5f * v * (1.0f + erff(v * 0.70710678118654752440f));
}

__device__ __forceinline__ double shfl_xor_dbl(double v, int m) {
    long long l = __double_as_longlong(v);
    int lo = (int)(l & 0xffffffffll);
    int hi = (int)(l >> 32);
    lo = __shfl_xor(lo, m, 64);
    hi = __shfl_xor(hi, m, 64);
    return __longlong_as_double(((long long)hi << 32) | (unsigned long long)(unsigned int)lo);
}

// ------- merged per-expert transpose+cast for w1 AND w2 (one launch) -------
// z<8: w1 expert z  (R=DM, C=HE);  z>=8: w2 expert z-8 (R=HE, C=DM)
__global__ void transpose_cast2_kernel(const float* __restrict__ w1,
                                       const float* __restrict__ w2,
                                       unsigned short* __restrict__ w1t,
                                       unsigned short* __restrict__ w2t) {
    __shared__ float tile[64][65];
    int z = blockIdx.z;
    const float* src; unsigned short* dst; int R, C, c0, r0;
    if (z < 8) {
        src = w1 + (size_t)z * DM * HE; dst = w1t + (size_t)z * DM * HE;
        R = DM; C = HE; c0 = blockIdx.x * 64; r0 = blockIdx.y * 64;
    } else {
        int e = z - 8;
        src = w2 + (size_t)e * HE * DM; dst = w2t + (size_t)e * HE * DM;
        R = HE; C = DM; c0 = blockIdx.y * 64; r0 = blockIdx.x * 64;
    }
    int tc = threadIdx.x & 63, tg = threadIdx.x >> 6;
    #pragma unroll
    for (int i = 0; i < 16; i++) {
        int r = tg * 16 + i;
        tile[r][tc] = src[(size_t)(r0 + r) * C + (c0 + tc)];
    }
    __syncthreads();
    #pragma unroll
    for (int i = 0; i < 16; i++) {
        int r = tg * 16 + i;
        dst[(size_t)(c0 + r) * R + (r0 + tc)] = f2bf(tile[tc][r]);
    }
}

// ---- fused gate (softmax+top2, fp64 acc) + x->bf16 cast: ONE pass over x ----
__global__ __launch_bounds__(256) void gate_cast_kernel(
        const float* __restrict__ x, const float* __restrict__ gw,
        unsigned short* __restrict__ xb,
        float* __restrict__ w_tok, int* __restrict__ e_sel) {
    __shared__ float gls[NE * GSTR];
    int tid = threadIdx.x;
    for (int v = tid; v < 2048; v += 256) {
        float4 g4 = ((const float4*)gw)[v];
        int idx = v * 4;
        int d = idx >> 3;
        int e0 = idx & 7;   // 0 or 4
        gls[(e0    ) * GSTR + d] = g4.x;
        gls[(e0 + 1) * GSTR + d] = g4.y;
        gls[(e0 + 2) * GSTR + d] = g4.z;
        gls[(e0 + 3) * GSTR + d] = g4.w;
    }
    __syncthreads();

    int n = blockIdx.x * 4 + (tid >> 6);
    int lane = tid & 63;
    const float4* xr = (const float4*)(x + (size_t)n * DM);
    ushort4* xw = (ushort4*)(xb + (size_t)n * DM);

    double s[NE];
    #pragma unroll
    for (int e = 0; e < NE; e++) s[e] = 0.0;

    #pragma unroll
    for (int i = 0; i < 4; i++) {
        float4 x4 = xr[i * 64 + lane];
        ushort4 o;
        o.x = f2bf(x4.x); o.y = f2bf(x4.y); o.z = f2bf(x4.z); o.w = f2bf(x4.w);
        xw[i * 64 + lane] = o;
        int d = (i * 64 + lane) * 4;
        #pragma unroll
        for (int e = 0; e < NE; e++) {
            float4 g4 = *(const float4*)(&gls[e * GSTR + d]);
            s[e] += (double)x4.x * (double)g4.x + (double)x4.y * (double)g4.y
                  + (double)x4.z * (double)g4.z + (double)x4.w * (double)g4.w;
        }
    }
    #pragma unroll
    for (int e = 0; e < NE; e++) {
        for (int off = 32; off > 0; off >>= 1)
            s[e] += shfl_xor_dbl(s[e], off);
    }
    if (lane == 0) {
        double m = s[0];
        for (int e = 1; e < NE; e++) if (s[e] > m) m = s[e];
        double sum = 0.0;
        for (int e = 0; e < NE; e++) sum += exp(s[e] - m);
        int i1 = 0; double v1 = s[0];
        for (int e = 1; e < NE; e++) if (s[e] > v1) { v1 = s[e]; i1 = e; }
        int i2 = -1; double v2 = -1e300;
        for (int e = 0; e < NE; e++) if (e != i1 && s[e] > v2) { v2 = s[e]; i2 = e; }
        w_tok[n] = (float)((exp(v1 - m) + exp(v2 - m)) / sum);
        e_sel[2 * n]     = i1;
        e_sel[2 * n + 1] = i2;
    }
}

// ------ routing: histogram + scan + scatter, ONE block, parallel LDS scan ------
__global__ __launch_bounds__(1024) void route_kernel(
        const int* __restrict__ e_sel, int* __restrict__ cnt, int* __restrict__ offs,
        int* __restrict__ pair_tok, int* __restrict__ slotmap) {
    __shared__ int wbin[16][NE];     // per-wave bins -> later per-wave cursors
    __shared__ int wstart[16][NE];
    __shared__ int etot[NE], eoffs[NE];
    int tid = threadIdx.x;
    int w = tid >> 6, l = tid & 63;
    if (l < NE) wbin[w][l] = 0;
    __syncthreads();

    int sel[16];
    #pragma unroll
    for (int k = 0; k < 16; k++) {
        sel[k] = e_sel[tid * 16 + k];
        atomicAdd(&wbin[w][sel[k]], 1);
    }
    __syncthreads();

    if (tid < NE) {                       // parallel over experts
        int t = 0;
        for (int ww = 0; ww < 16; ww++) t += wbin[ww][tid];
        etot[tid] = t;
    }
    __syncthreads();
    if (tid == 0) {                       // tiny 8-elem exclusive scan
        int a = 0;
        for (int e = 0; e < NE; e++) { eoffs[e] = a; a += etot[e]; }
    }
    __syncthreads();
    if (tid < NE) {                       // parallel over experts
        cnt[tid] = etot[tid];
        offs[tid] = eoffs[tid];
        int r = eoffs[tid];
        for (int ww = 0; ww < 16; ww++) { wstart[ww][tid] = r; r += wbin[ww][tid]; }
    }
    __syncthreads();
    if (l < NE) wbin[w][l] = wstart[w][l];   // reuse as cursors
    __syncthreads();

    #pragma unroll
    for (int k = 0; k < 16; k++) {
        int i = tid * 16 + k;
        int slot = atomicAdd(&wbin[w][sel[k]], 1);
        pair_tok[slot] = i >> 1;
        slotmap[i] = slot;
    }
}

// ---------------- GEMM1: h = gelu(x_gathered @ w1[e] + b1[e]) ----------------
// Double-buffered LDS + raw s_barrier + fine-grained vmcnt: loads for iter k+1
// stay in flight across the barrier (no vmcnt(0) drain).
__global__ __launch_bounds__(256, 2) void gemm1_kernel(
        const unsigned short* __restrict__ xb,      // [N_TOK][DM] bf16
        const unsigned short* __restrict__ w1t,     // [E][HE][DM] bf16 (B^T layout)
        const float* __restrict__ b1,               // [E][HE]
        const int* __restrict__ pair_tok,
        const int* __restrict__ cnt, const int* __restrict__ offs,
        unsigned short* __restrict__ hbuf) {        // [NPAIR][HE] bf16
    int e = blockIdx.z;
    int cn = cnt[e];
    int m0 = blockIdx.y * BM;
    if (m0 >= cn) return;
    int n0 = blockIdx.x * BN;
    int base = offs[e];

    __shared__ __align__(16) unsigned short As[2 * BM * BK];   // 32 KB
    __shared__ __align__(16) unsigned short Bs[2 * BN * BK];   // 32 KB

    int tid = threadIdx.x;
    int lane = tid & 63;
    int w = tid >> 6;
    int wu = __builtin_amdgcn_readfirstlane(w);
    int l3 = lane >> 3, l7 = lane & 7;
    int g = l7 ^ l3;               // swizzled source k-group for this lane

    // per-lane global source base addresses (row fixed over K-loop); tks in regs
    const char* aptr[4];
    const char* bptr[4];
    #pragma unroll
    for (int j = 0; j < 4; j++) {
        int row = w * 32 + j * 8 + l3;
        int r = m0 + row;
        int t = pair_tok[base + (r < cn ? r : 0)];
        aptr[j] = (const char*)xb  + (size_t)t * (DM * 2) + g * 16;
        bptr[j] = (const char*)w1t + ((size_t)e * HE + n0 + row) * (DM * 2) + g * 16;
    }

    int wm = (w & 1) * 64;
    int wn = (w >> 1) * 64;
    int fr = lane & 15;
    int fq = lane >> 4;

    f32x4 acc[4][4];
    #pragma unroll
    for (int i = 0; i < 4; i++)
        #pragma unroll
        for (int j = 0; j < 4; j++)
            acc[i][j] = (f32x4){0.f, 0.f, 0.f, 0.f};

    // prologue: iter 0 -> buf 0
    #pragma unroll
    for (int j = 0; j < 4; j++) {
        gl_lds16(aptr[j], (char*)As + wu * 4096 + j * 1024);
        gl_lds16(bptr[j], (char*)Bs + wu * 4096 + j * 1024);
    }

    for (int it = 0; it < DM / BK; it++) {
        int p = it & 1;
        if (it + 1 < DM / BK) {
            int kb = (it + 1) * (BK * 2);
            #pragma unroll
            for (int j = 0; j < 4; j++) {
                gl_lds16(aptr[j] + kb, (char*)As + (p ^ 1) * 16384 + wu * 4096 + j * 1024);
                gl_lds16(bptr[j] + kb, (char*)Bs + (p ^ 1) * 16384 + wu * 4096 + j * 1024);
            }
            asm volatile("s_waitcnt vmcnt(8)" ::: "memory");   // iter-it loads done
        } else {
            asm volatile("s_waitcnt vmcnt(0)" ::: "memory");
        }
        __builtin_amdgcn_s_barrier();       // buf p filled for ALL waves
        const char* ab = (const char*)As + p * 16384;
        const char* bb = (const char*)Bs + p * 16384;
        #pragma unroll
        for (int kk2 = 0; kk2 < 2; kk2++) {
            int sw = ((kk2 * 4 + fq) ^ (fr & 7)) << 4;   // swizzled byte group
            bf16x8 af[4], bfv[4];
            #pragma unroll
            for (int i = 0; i < 4; i++)
                af[i] = *(const bf16x8*)(ab + (wm + i * 16 + fr) * 128 + sw);
            #pragma unroll
            for (int j = 0; j < 4; j++)
                bfv[j] = *(const bf16x8*)(bb + (wn + j * 16 + fr) * 128 + sw);
            #pragma unroll
            for (int i = 0; i < 4; i++)
                #pragma unroll
                for (int j = 0; j < 4; j++)
                    acc[i][j] = __builtin_amdgcn_mfma_f32_16x16x32_bf16(af[i], bfv[j], acc[i][j], 0, 0, 0);
        }
        __builtin_amdgcn_s_barrier();       // all waves done reading buf p
    }

    #pragma unroll
    for (int j = 0; j < 4; j++) {
        int nn = n0 + wn + j * 16 + fr;          // h index (C/D col = lane&15)
        float bias = b1[e * HE + nn];
        #pragma unroll
        for (int i = 0; i < 4; i++) {
            #pragma unroll
            for (int r = 0; r < 4; r++) {
                int mm = wm + i * 16 + fq * 4 + r;  // C/D row = quad*4+reg
                if (m0 + mm < cn) {
                    float v = acc[i][j][r] + bias;
                    hbuf[(size_t)(base + m0 + mm) * HE + nn] = f2bf(gelu_exact(v));
                }
            }
        }
    }
}

// -------- GEMM2: ybuf[slot] = w_tok * (h @ w2[e] + b2[e])  (bf16, no atomics) --------
// Single-buffered, but 4 blocks/CU (grid has 1024 active blocks).
__global__ __launch_bounds__(256, 4) void gemm2_kernel(
        const unsigned short* __restrict__ hbuf,    // [NPAIR][HE] bf16
        const unsigned short* __restrict__ w2t,     // [E][DM][HE] bf16 (B^T layout)
        const float* __restrict__ b2,               // [E][DM]
        const int* __restrict__ pair_tok,
        const float* __restrict__ w_tok,
        const int* __restrict__ cnt, const int* __restrict__ offs,
        unsigned short* __restrict__ ybuf) {        // [NPAIR][DM] bf16
    int e = blockIdx.z;
    int cn = cnt[e];
    int m0 = blockIdx.y * BM;
    if (m0 >= cn) return;
    int n0 = blockIdx.x * BN;
    int base = offs[e];

    __shared__ __align__(16) unsigned short As[BM * BK];
    __shared__ __align__(16) unsigned short Bs[BN * BK];
    __shared__ float wts[BM];

    int tid = threadIdx.x;
    if (tid < BM) {
        int r = m0 + tid;
        int rr = (r < cn ? r : cn - 1);
        wts[tid] = w_tok[pair_tok[base + rr]];
    }
    __syncthreads();

    int lane = tid & 63;
    int w = tid >> 6;
    int wu = __builtin_amdgcn_readfirstlane(w);
    int l3 = lane >> 3, l7 = lane & 7;
    int g = l7 ^ l3;

    const char* aptr[4];
    const char* bptr[4];
    #pragma unroll
    for (int j = 0; j < 4; j++) {
        int row = w * 32 + j * 8 + l3;
        int crow = (m0 + row < cn) ? row : 0;                       // clamp OOB rows
        aptr[j] = (const char*)hbuf + (size_t)(base + m0 + crow) * (HE * 2) + g * 16;
        bptr[j] = (const char*)w2t  + ((size_t)e * DM + n0 + row) * (HE * 2) + g * 16;
    }

    int wm = (w & 1) * 64;
    int wn = (w >> 1) * 64;
    int fr = lane & 15;
    int fq = lane >> 4;

    f32x4 acc[4][4];
    #pragma unroll
    for (int i = 0; i < 4; i++)
        #pragma unroll
        for (int j = 0; j < 4; j++)
            acc[i][j] = (f32x4){0.f, 0.f, 0.f, 0.f};

    for (int k0 = 0; k0 < HE; k0 += BK) {
        int kb = k0 * 2;
        #pragma unroll
        for (int j = 0; j < 4; j++) {
            gl_lds16(aptr[j] + kb, (char*)As + wu * 4096 + j * 1024);
            gl_lds16(bptr[j] + kb, (char*)Bs + wu * 4096 + j * 1024);
        }
        __syncthreads();
        #pragma unroll
        for (int kk2 = 0; kk2 < 2; kk2++) {
            int sw = ((kk2 * 4 + fq) ^ (fr & 7)) << 4;
            bf16x8 af[4], bfv[4];
            #pragma unroll
            for (int i = 0; i < 4; i++)
                af[i] = *(const bf16x8*)((const char*)As + (wm + i * 16 + fr) * 128 + sw);
            #pragma unroll
            for (int j = 0; j < 4; j++)
                bfv[j] = *(const bf16x8*)((const char*)Bs + (wn + j * 16 + fr) * 128 + sw);
            #pragma unroll
            for (int i = 0; i < 4; i++)
                #pragma unroll
                for (int j = 0; j < 4; j++)
                    acc[i][j] = __builtin_amdgcn_mfma_f32_16x16x32_bf16(af[i], bfv[j], acc[i][j], 0, 0, 0);
        }
        __syncthreads();
    }

    #pragma unroll
    for (int j = 0; j < 4; j++) {
        int dd = n0 + wn + j * 16 + fr;           // output-dim col
        float bias = b2[e * DM + dd];
        #pragma unroll
        for (int i = 0; i < 4; i++) {
            #pragma unroll
            for (int r = 0; r < 4; r++) {
                int mm = wm + i * 16 + fq * 4 + r;
                if (m0 + mm < cn) {
                    float wgt = wts[mm];
                    ybuf[(size_t)(base + m0 + mm) * DM + dd] = f2bf(wgt * (acc[i][j][r] + bias));
                }
            }
        }
    }
}

// ---------------- combine: out[n] = yb[slot1] + yb[slot2] ----------------
__global__ void combine_kernel(const unsigned short* __restrict__ yb,
                               const int* __restrict__ slotmap,
                               float* __restrict__ out) {
    int i = blockIdx.x * 256 + threadIdx.x;
    int n = i >> 8;
    int c = (i & 255) * 4;
    int s1 = slotmap[2 * n];
    int s2 = slotmap[2 * n + 1];
    ushort4 a = *(const ushort4*)(&yb[(size_t)s1 * DM + c]);
    ushort4 b = *(const ushort4*)(&yb[(size_t)s2 * DM + c]);
    float4 o;
    o.x = bf2f(a.x) + bf2f(b.x);
    o.y = bf2f(a.y) + bf2f(b.y);
    o.z = bf2f(a.z) + bf2f(b.z);
    o.w = bf2f(a.w) + bf2f(b.w);
    ((float4*)out)[i] = o;
}

extern "C" void kernel_launch(void* const* d_in, const int* in_sizes, int n_in,
                              void* d_out, int out_size, void* d_ws, size_t ws_size,
                              hipStream_t stream) {
    const float* x  = (const float*)d_in[0];
    const float* gw = (const float*)d_in[1];
    const float* w1 = (const float*)d_in[2];
    const float* b1 = (const float*)d_in[3];
    const float* w2 = (const float*)d_in[4];
    const float* b2 = (const float*)d_in[5];
    float* out = (float*)d_out;

    char* ws = (char*)d_ws;
    // ws layout (bytes), total ~59 MB.
    // ybuf (33.5 MB) overlays xb + w1t: both dead by the time gemm2 runs.
    unsigned short* ybuf = (unsigned short*)(ws);              // 33,554,432 [NPAIR][DM] bf16
    unsigned short* xb   = (unsigned short*)(ws);              // 16,777,216 (dead after gemm1)
    unsigned short* w1t  = (unsigned short*)(ws + 16777216);   //  8,388,608 (dead after gemm1)
    unsigned short* w2t  = (unsigned short*)(ws + 33554432);   //  8,388,608  [e][d][h]
    unsigned short* hbuf = (unsigned short*)(ws + 41943040);   // 16,777,216  [NPAIR][HE]
    float* w_tok         = (float*)(ws + 58720256);            //     32,768
    int*   e_sel         = (int*)(ws + 58753024);              //     65,536
    int*   slotmap       = (int*)(ws + 58818560);              //     65,536
    int*   cnt           = (int*)(ws + 58884096);              //         32
    int*   offs          = (int*)(ws + 58884128);              //         32
    int*   pair_tok      = (int*)(ws + 58884224);              //     65,536

    transpose_cast2_kernel<<<dim3(8, 16, 16), 256, 0, stream>>>(w1, w2, w1t, w2t);
    gate_cast_kernel<<<N_TOK / 4, 256, 0, stream>>>(x, gw, xb, w_tok, e_sel);
    route_kernel<<<1, 1024, 0, stream>>>(e_sel, cnt, offs, pair_tok, slotmap);
    gemm1_kernel<<<dim3(HE / BN, N_TOK / BM, NE), 256, 0, stream>>>(
        xb, w1t, b1, pair_tok, cnt, offs, hbuf);
    gemm2_kernel<<<dim3(DM / BN, N_TOK / BM, NE), 256, 0, stream>>>(
        hbuf, w2t, b2, pair_tok, w_tok, cnt, offs, ybuf);
    combine_kernel<<<(N_TOK * DM / 4) / 256, 256, 0, stream>>>(ybuf, slotmap, out);
}

// Round 6
// 235.321 us; speedup vs baseline: 2.5494x; 1.1047x over previous
//
#include <hip/hip_runtime.h>
#include <math.h>

#define N_TOK 8192
#define DM 1024
#define NE 8
#define HE 512
#define NPAIR 16384
#define MAXMB 264      // max M-blocks: sum_e ceil(cnt_e/64) <= 256 + 8

#define BM 64
#define BN 128
#define BK 64          // 64 bf16 = 128 B per LDS row, unpadded (global_load_lds contiguity)

#define GSTR 1028      // gate LDS row stride (fp32 elems)

typedef __bf16 bf16x8 __attribute__((ext_vector_type(8)));
typedef float f32x4 __attribute__((ext_vector_type(4)));

#define GLOBAL_AS __attribute__((address_space(1)))
#define LDS_AS    __attribute__((address_space(3)))

__device__ __forceinline__ void gl_lds16(const void* g, void* lds) {
    __builtin_amdgcn_global_load_lds((const GLOBAL_AS unsigned int*)g,
                                     (LDS_AS unsigned int*)lds, 16, 0, 0);
}

__device__ __forceinline__ unsigned short f2bf(float f) {
    unsigned int u = __float_as_uint(f);
    u += 0x7fffu + ((u >> 16) & 1u);   // RNE; inputs finite
    return (unsigned short)(u >> 16);
}

__device__ __forceinline__ float bf2f(unsigned short u) {
    return __uint_as_float(((unsigned int)u) << 16);
}

__device__ __forceinline__ float gelu_exact(float v) {
    return 0.5f * v * (1.0f + erff(v * 0.70710678118654752440f));
}

__device__ __forceinline__ double shfl_xor_dbl(double v, int m) {
    long long l = __double_as_longlong(v);
    int lo = (int)(l & 0xffffffffll);
    int hi = (int)(l >> 32);
    lo = __shfl_xor(lo, m, 64);
    hi = __shfl_xor(hi, m, 64);
    return __longlong_as_double(((long long)hi << 32) | (unsigned long long)(unsigned int)lo);
}

// ------- merged per-expert transpose+cast for w1 AND w2 (one launch) -------
__global__ void transpose_cast2_kernel(const float* __restrict__ w1,
                                       const float* __restrict__ w2,
                                       unsigned short* __restrict__ w1t,
                                       unsigned short* __restrict__ w2t) {
    __shared__ float tile[64][65];
    int z = blockIdx.z;
    const float* src; unsigned short* dst; int R, C, c0, r0;
    if (z < 8) {
        src = w1 + (size_t)z * DM * HE; dst = w1t + (size_t)z * DM * HE;
        R = DM; C = HE; c0 = blockIdx.x * 64; r0 = blockIdx.y * 64;
    } else {
        int e = z - 8;
        src = w2 + (size_t)e * HE * DM; dst = w2t + (size_t)e * HE * DM;
        R = HE; C = DM; c0 = blockIdx.y * 64; r0 = blockIdx.x * 64;
    }
    int tc = threadIdx.x & 63, tg = threadIdx.x >> 6;
    #pragma unroll
    for (int i = 0; i < 16; i++) {
        int r = tg * 16 + i;
        tile[r][tc] = src[(size_t)(r0 + r) * C + (c0 + tc)];
    }
    __syncthreads();
    #pragma unroll
    for (int i = 0; i < 16; i++) {
        int r = tg * 16 + i;
        dst[(size_t)(c0 + r) * R + (r0 + tc)] = f2bf(tile[tc][r]);
    }
}

// ---- fused gate (softmax+top2, fp64 acc) + x->bf16 cast: ONE pass over x ----
__global__ __launch_bounds__(256) void gate_cast_kernel(
        const float* __restrict__ x, const float* __restrict__ gw,
        unsigned short* __restrict__ xb,
        float* __restrict__ w_tok, int* __restrict__ e_sel) {
    __shared__ float gls[NE * GSTR];
    int tid = threadIdx.x;
    for (int v = tid; v < 2048; v += 256) {
        float4 g4 = ((const float4*)gw)[v];
        int idx = v * 4;
        int d = idx >> 3;
        int e0 = idx & 7;   // 0 or 4
        gls[(e0    ) * GSTR + d] = g4.x;
        gls[(e0 + 1) * GSTR + d] = g4.y;
        gls[(e0 + 2) * GSTR + d] = g4.z;
        gls[(e0 + 3) * GSTR + d] = g4.w;
    }
    __syncthreads();

    int n = blockIdx.x * 4 + (tid >> 6);
    int lane = tid & 63;
    const float4* xr = (const float4*)(x + (size_t)n * DM);
    ushort4* xw = (ushort4*)(xb + (size_t)n * DM);

    double s[NE];
    #pragma unroll
    for (int e = 0; e < NE; e++) s[e] = 0.0;

    #pragma unroll
    for (int i = 0; i < 4; i++) {
        float4 x4 = xr[i * 64 + lane];
        ushort4 o;
        o.x = f2bf(x4.x); o.y = f2bf(x4.y); o.z = f2bf(x4.z); o.w = f2bf(x4.w);
        xw[i * 64 + lane] = o;
        int d = (i * 64 + lane) * 4;
        #pragma unroll
        for (int e = 0; e < NE; e++) {
            float4 g4 = *(const float4*)(&gls[e * GSTR + d]);
            s[e] += (double)x4.x * (double)g4.x + (double)x4.y * (double)g4.y
                  + (double)x4.z * (double)g4.z + (double)x4.w * (double)g4.w;
        }
    }
    #pragma unroll
    for (int e = 0; e < NE; e++) {
        for (int off = 32; off > 0; off >>= 1)
            s[e] += shfl_xor_dbl(s[e], off);
    }
    if (lane == 0) {
        double m = s[0];
        for (int e = 1; e < NE; e++) if (s[e] > m) m = s[e];
        double sum = 0.0;
        for (int e = 0; e < NE; e++) sum += exp(s[e] - m);
        int i1 = 0; double v1 = s[0];
        for (int e = 1; e < NE; e++) if (s[e] > v1) { v1 = s[e]; i1 = e; }
        int i2 = -1; double v2 = -1e300;
        for (int e = 0; e < NE; e++) if (e != i1 && s[e] > v2) { v2 = s[e]; i2 = e; }
        w_tok[n] = (float)((exp(v1 - m) + exp(v2 - m)) / sum);
        e_sel[2 * n]     = i1;
        e_sel[2 * n + 1] = i2;
    }
}

// ------ routing: histogram + scan + scatter + per-M-block tables, ONE block ------
__global__ __launch_bounds__(1024) void route_kernel(
        const int* __restrict__ e_sel, int* __restrict__ cnt, int* __restrict__ offs,
        int* __restrict__ pair_tok, int* __restrict__ slotmap,
        int* __restrict__ mb_e, int* __restrict__ mb_base, int* __restrict__ n_mb) {
    __shared__ int wbin[16][NE];     // per-wave bins -> later per-wave cursors
    __shared__ int wstart[16][NE];
    __shared__ int etot[NE], eoffs[NE], bofs[NE];
    int tid = threadIdx.x;
    int w = tid >> 6, l = tid & 63;
    if (l < NE) wbin[w][l] = 0;
    __syncthreads();

    int sel[16];
    #pragma unroll
    for (int k = 0; k < 16; k++) {
        sel[k] = e_sel[tid * 16 + k];
        atomicAdd(&wbin[w][sel[k]], 1);
    }
    __syncthreads();

    if (tid < NE) {                       // parallel over experts
        int t = 0;
        for (int ww = 0; ww < 16; ww++) t += wbin[ww][tid];
        etot[tid] = t;
    }
    __syncthreads();
    if (tid == 0) {                       // tiny 8-elem scans
        int a = 0, b = 0;
        for (int e = 0; e < NE; e++) {
            eoffs[e] = a; a += etot[e];
            bofs[e] = b;  b += (etot[e] + BM - 1) / BM;
        }
        n_mb[0] = b;
    }
    __syncthreads();
    if (tid < NE) {                       // parallel over experts
        cnt[tid] = etot[tid];
        offs[tid] = eoffs[tid];
        int r = eoffs[tid];
        for (int ww = 0; ww < 16; ww++) { wstart[ww][tid] = r; r += wbin[ww][tid]; }
        int nb = (etot[tid] + BM - 1) / BM;
        int b0 = bofs[tid];
        for (int b = 0; b < nb; b++) {    // <=33 entries per expert
            mb_e[b0 + b] = tid;
            mb_base[b0 + b] = eoffs[tid] + b * BM;
        }
    }
    __syncthreads();
    if (l < NE) wbin[w][l] = wstart[w][l];   // reuse as cursors
    __syncthreads();

    #pragma unroll
    for (int k = 0; k < 16; k++) {
        int i = tid * 16 + k;
        int slot = atomicAdd(&wbin[w][sel[k]], 1);
        pair_tok[slot] = i >> 1;
        slotmap[i] = slot;
    }
}

// ---------------- GEMM1: h = gelu(x_gathered @ w1[e] + b1[e]) ----------------
// 64x128 tile, single-buffered LDS (24 KB), dense grid via mb tables, 4 blocks/CU.
__global__ __launch_bounds__(256, 4) void gemm1_kernel(
        const unsigned short* __restrict__ xb,      // [N_TOK][DM] bf16
        const unsigned short* __restrict__ w1t,     // [E][HE][DM] bf16 (B^T layout)
        const float* __restrict__ b1,               // [E][HE]
        const int* __restrict__ pair_tok,
        const int* __restrict__ cnt, const int* __restrict__ offs,
        const int* __restrict__ mb_e, const int* __restrict__ mb_base,
        const int* __restrict__ n_mb,
        unsigned short* __restrict__ hbuf) {        // [NPAIR][HE] bf16
    int mb = blockIdx.y;
    if (mb >= n_mb[0]) return;
    int e = mb_e[mb];
    int sbase = mb_base[mb];
    int vlim = offs[e] + cnt[e];
    int n0 = blockIdx.x * BN;

    __shared__ __align__(16) unsigned short As[BM * BK];   //  8 KB
    __shared__ __align__(16) unsigned short Bs[BN * BK];   // 16 KB

    int tid = threadIdx.x;
    int lane = tid & 63;
    int w = tid >> 6;
    int wu = __builtin_amdgcn_readfirstlane(w);
    int l3 = lane >> 3, l7 = lane & 7;
    int g = l7 ^ l3;               // swizzled source k-group for this lane

    const char* aptr[2];
    const char* bptr[4];
    #pragma unroll
    for (int j = 0; j < 2; j++) {
        int row = w * 16 + j * 8 + l3;
        int slot = sbase + row;
        int t = pair_tok[slot < vlim ? slot : vlim - 1];
        aptr[j] = (const char*)xb + (size_t)t * (DM * 2) + g * 16;
    }
    #pragma unroll
    for (int j = 0; j < 4; j++) {
        int row = w * 32 + j * 8 + l3;
        bptr[j] = (const char*)w1t + ((size_t)e * HE + n0 + row) * (DM * 2) + g * 16;
    }

    int wm = (w & 1) * 32;
    int wn = (w >> 1) * 64;
    int fr = lane & 15;
    int fq = lane >> 4;

    f32x4 acc[2][4];
    #pragma unroll
    for (int i = 0; i < 2; i++)
        #pragma unroll
        for (int j = 0; j < 4; j++)
            acc[i][j] = (f32x4){0.f, 0.f, 0.f, 0.f};

    for (int k0 = 0; k0 < DM; k0 += BK) {
        int kb = k0 * 2;
        #pragma unroll
        for (int j = 0; j < 2; j++)
            gl_lds16(aptr[j] + kb, (char*)As + wu * 2048 + j * 1024);
        #pragma unroll
        for (int j = 0; j < 4; j++)
            gl_lds16(bptr[j] + kb, (char*)Bs + wu * 4096 + j * 1024);
        __syncthreads();   // drains vmcnt: LDS tiles ready
        #pragma unroll
        for (int kk2 = 0; kk2 < 2; kk2++) {
            int sw = ((kk2 * 4 + fq) ^ (fr & 7)) << 4;   // swizzled byte group
            bf16x8 af[2], bfv[4];
            #pragma unroll
            for (int i = 0; i < 2; i++)
                af[i] = *(const bf16x8*)((const char*)As + (wm + i * 16 + fr) * 128 + sw);
            #pragma unroll
            for (int j = 0; j < 4; j++)
                bfv[j] = *(const bf16x8*)((const char*)Bs + (wn + j * 16 + fr) * 128 + sw);
            #pragma unroll
            for (int i = 0; i < 2; i++)
                #pragma unroll
                for (int j = 0; j < 4; j++)
                    acc[i][j] = __builtin_amdgcn_mfma_f32_16x16x32_bf16(af[i], bfv[j], acc[i][j], 0, 0, 0);
        }
        __syncthreads();   // all waves done reading before next stage overwrites
    }

    #pragma unroll
    for (int j = 0; j < 4; j++) {
        int nn = n0 + wn + j * 16 + fr;          // h index (C/D col = lane&15)
        float bias = b1[e * HE + nn];
        #pragma unroll
        for (int i = 0; i < 2; i++) {
            #pragma unroll
            for (int r = 0; r < 4; r++) {
                int mm = wm + i * 16 + fq * 4 + r;  // C/D row = quad*4+reg
                if (sbase + mm < vlim) {
                    float v = acc[i][j][r] + bias;
                    hbuf[(size_t)(sbase + mm) * HE + nn] = f2bf(gelu_exact(v));
                }
            }
        }
    }
}

// -------- GEMM2: ybuf[slot] = w_tok * (h @ w2[e] + b2[e])  (bf16, no atomics) --------
__global__ __launch_bounds__(256, 4) void gemm2_kernel(
        const unsigned short* __restrict__ hbuf,    // [NPAIR][HE] bf16
        const unsigned short* __restrict__ w2t,     // [E][DM][HE] bf16 (B^T layout)
        const float* __restrict__ b2,               // [E][DM]
        const int* __restrict__ pair_tok,
        const float* __restrict__ w_tok,
        const int* __restrict__ cnt, const int* __restrict__ offs,
        const int* __restrict__ mb_e, const int* __restrict__ mb_base,
        const int* __restrict__ n_mb,
        unsigned short* __restrict__ ybuf) {        // [NPAIR][DM] bf16
    int mb = blockIdx.y;
    if (mb >= n_mb[0]) return;
    int e = mb_e[mb];
    int sbase = mb_base[mb];
    int vlim = offs[e] + cnt[e];
    int n0 = blockIdx.x * BN;

    __shared__ __align__(16) unsigned short As[BM * BK];   //  8 KB
    __shared__ __align__(16) unsigned short Bs[BN * BK];   // 16 KB
    __shared__ float wts[BM];

    int tid = threadIdx.x;
    if (tid < BM) {
        int slot = sbase + tid;
        wts[tid] = w_tok[pair_tok[slot < vlim ? slot : vlim - 1]];
    }
    __syncthreads();

    int lane = tid & 63;
    int w = tid >> 6;
    int wu = __builtin_amdgcn_readfirstlane(w);
    int l3 = lane >> 3, l7 = lane & 7;
    int g = l7 ^ l3;

    const char* aptr[2];
    const char* bptr[4];
    #pragma unroll
    for (int j = 0; j < 2; j++) {
        int row = w * 16 + j * 8 + l3;
        int slot = sbase + row;
        int cs = (slot < vlim) ? slot : vlim - 1;   // clamp OOB rows
        aptr[j] = (const char*)hbuf + (size_t)cs * (HE * 2) + g * 16;
    }
    #pragma unroll
    for (int j = 0; j < 4; j++) {
        int row = w * 32 + j * 8 + l3;
        bptr[j] = (const char*)w2t + ((size_t)e * DM + n0 + row) * (HE * 2) + g * 16;
    }

    int wm = (w & 1) * 32;
    int wn = (w >> 1) * 64;
    int fr = lane & 15;
    int fq = lane >> 4;

    f32x4 acc[2][4];
    #pragma unroll
    for (int i = 0; i < 2; i++)
        #pragma unroll
        for (int j = 0; j < 4; j++)
            acc[i][j] = (f32x4){0.f, 0.f, 0.f, 0.f};

    for (int k0 = 0; k0 < HE; k0 += BK) {
        int kb = k0 * 2;
        #pragma unroll
        for (int j = 0; j < 2; j++)
            gl_lds16(aptr[j] + kb, (char*)As + wu * 2048 + j * 1024);
        #pragma unroll
        for (int j = 0; j < 4; j++)
            gl_lds16(bptr[j] + kb, (char*)Bs + wu * 4096 + j * 1024);
        __syncthreads();
        #pragma unroll
        for (int kk2 = 0; kk2 < 2; kk2++) {
            int sw = ((kk2 * 4 + fq) ^ (fr & 7)) << 4;
            bf16x8 af[2], bfv[4];
            #pragma unroll
            for (int i = 0; i < 2; i++)
                af[i] = *(const bf16x8*)((const char*)As + (wm + i * 16 + fr) * 128 + sw);
            #pragma unroll
            for (int j = 0; j < 4; j++)
                bfv[j] = *(const bf16x8*)((const char*)Bs + (wn + j * 16 + fr) * 128 + sw);
            #pragma unroll
            for (int i = 0; i < 2; i++)
                #pragma unroll
                for (int j = 0; j < 4; j++)
                    acc[i][j] = __builtin_amdgcn_mfma_f32_16x16x32_bf16(af[i], bfv[j], acc[i][j], 0, 0, 0);
        }
        __syncthreads();
    }

    #pragma unroll
    for (int j = 0; j < 4; j++) {
        int dd = n0 + wn + j * 16 + fr;           // output-dim col
        float bias = b2[e * DM + dd];
        #pragma unroll
        for (int i = 0; i < 2; i++) {
            #pragma unroll
            for (int r = 0; r < 4; r++) {
                int mm = wm + i * 16 + fq * 4 + r;
                if (sbase + mm < vlim) {
                    float wgt = wts[mm];
                    ybuf[(size_t)(sbase + mm) * DM + dd] = f2bf(wgt * (acc[i][j][r] + bias));
                }
            }
        }
    }
}

// ---------------- combine: out[n] = yb[slot1] + yb[slot2] ----------------
__global__ void combine_kernel(const unsigned short* __restrict__ yb,
                               const int* __restrict__ slotmap,
                               float* __restrict__ out) {
    int i = blockIdx.x * 256 + threadIdx.x;
    int n = i >> 8;
    int c = (i & 255) * 4;
    int s1 = slotmap[2 * n];
    int s2 = slotmap[2 * n + 1];
    ushort4 a = *(const ushort4*)(&yb[(size_t)s1 * DM + c]);
    ushort4 b = *(const ushort4*)(&yb[(size_t)s2 * DM + c]);
    float4 o;
    o.x = bf2f(a.x) + bf2f(b.x);
    o.y = bf2f(a.y) + bf2f(b.y);
    o.z = bf2f(a.z) + bf2f(b.z);
    o.w = bf2f(a.w) + bf2f(b.w);
    ((float4*)out)[i] = o;
}

extern "C" void kernel_launch(void* const* d_in, const int* in_sizes, int n_in,
                              void* d_out, int out_size, void* d_ws, size_t ws_size,
                              hipStream_t stream) {
    const float* x  = (const float*)d_in[0];
    const float* gw = (const float*)d_in[1];
    const float* w1 = (const float*)d_in[2];
    const float* b1 = (const float*)d_in[3];
    const float* w2 = (const float*)d_in[4];
    const float* b2 = (const float*)d_in[5];
    float* out = (float*)d_out;

    char* ws = (char*)d_ws;
    // ws layout (bytes), total ~59 MB.
    // ybuf (33.5 MB) overlays xb + w1t: both dead by the time gemm2 runs.
    unsigned short* ybuf = (unsigned short*)(ws);              // 33,554,432 [NPAIR][DM] bf16
    unsigned short* xb   = (unsigned short*)(ws);              // 16,777,216 (dead after gemm1)
    unsigned short* w1t  = (unsigned short*)(ws + 16777216);   //  8,388,608 (dead after gemm1)
    unsigned short* w2t  = (unsigned short*)(ws + 33554432);   //  8,388,608  [e][d][h]
    unsigned short* hbuf = (unsigned short*)(ws + 41943040);   // 16,777,216  [NPAIR][HE]
    float* w_tok         = (float*)(ws + 58720256);            //     32,768
    int*   e_sel         = (int*)(ws + 58753024);              //     65,536
    int*   slotmap       = (int*)(ws + 58818560);              //     65,536
    int*   cnt           = (int*)(ws + 58884096);              //         32
    int*   offs          = (int*)(ws + 58884128);              //         32
    int*   pair_tok      = (int*)(ws + 58884224);              //     65,536
    int*   mb_e          = (int*)(ws + 58949760);              //      1,088
    int*   mb_base       = (int*)(ws + 58950848);              //      1,088
    int*   n_mb          = (int*)(ws + 58951936);              //          4

    transpose_cast2_kernel<<<dim3(8, 16, 16), 256, 0, stream>>>(w1, w2, w1t, w2t);
    gate_cast_kernel<<<N_TOK / 4, 256, 0, stream>>>(x, gw, xb, w_tok, e_sel);
    route_kernel<<<1, 1024, 0, stream>>>(e_sel, cnt, offs, pair_tok, slotmap,
                                         mb_e, mb_base, n_mb);
    gemm1_kernel<<<dim3(HE / BN, MAXMB), 256, 0, stream>>>(
        xb, w1t, b1, pair_tok, cnt, offs, mb_e, mb_base, n_mb, hbuf);
    gemm2_kernel<<<dim3(DM / BN, MAXMB), 256, 0, stream>>>(
        hbuf, w2t, b2, pair_tok, w_tok, cnt, offs, mb_e, mb_base, n_mb, ybuf);
    combine_kernel<<<(N_TOK * DM / 4) / 256, 256, 0, stream>>>(ybuf, slotmap, out);
}

// Round 7
// 221.977 us; speedup vs baseline: 2.7026x; 1.0601x over previous
//
#include <hip/hip_runtime.h>
#include <math.h>

#define N_TOK 8192
#define DM 1024
#define NE 8
#define HE 512
#define NPAIR 16384
#define MAXMB 264      // max M-blocks: sum_e ceil(cnt_e/64) <= 256 + 8

#define BM 64
#define BN 128
#define BK 64          // 64 bf16 = 128 B per LDS row, unpadded (global_load_lds contiguity)
#define OSTR 136       // epilogue LDS tile row stride (elems): 272 B, 2-way-only conflicts

#define GSTR 1028      // gate LDS row stride (fp32 elems)

typedef __bf16 bf16x8 __attribute__((ext_vector_type(8)));
typedef float f32x4 __attribute__((ext_vector_type(4)));

#define GLOBAL_AS __attribute__((address_space(1)))
#define LDS_AS    __attribute__((address_space(3)))

__device__ __forceinline__ void gl_lds16(const void* g, void* lds) {
    __builtin_amdgcn_global_load_lds((const GLOBAL_AS unsigned int*)g,
                                     (LDS_AS unsigned int*)lds, 16, 0, 0);
}

__device__ __forceinline__ unsigned short f2bf(float f) {
    unsigned int u = __float_as_uint(f);
    u += 0x7fffu + ((u >> 16) & 1u);   // RNE; inputs finite
    return (unsigned short)(u >> 16);
}

__device__ __forceinline__ float gelu_exact(float v) {
    return 0.5f * v * (1.0f + erff(v * 0.70710678118654752440f));
}

__device__ __forceinline__ double shfl_xor_dbl(double v, int m) {
    long long l = __double_as_longlong(v);
    int lo = (int)(l & 0xffffffffll);
    int hi = (int)(l >> 32);
    lo = __shfl_xor(lo, m, 64);
    hi = __shfl_xor(hi, m, 64);
    return __longlong_as_double(((long long)hi << 32) | (unsigned long long)(unsigned int)lo);
}

// ---- fused: gate (softmax+top2, fp64 acc) + x->bf16 cast + w1/w2 transpose ----
// blocks [0,2048): gate+cast (4 tokens each). blocks [2048,4096): transpose.
__global__ __launch_bounds__(256) void prep_kernel(
        const float* __restrict__ x, const float* __restrict__ gw,
        const float* __restrict__ w1, const float* __restrict__ w2,
        unsigned short* __restrict__ xb,
        unsigned short* __restrict__ w1t, unsigned short* __restrict__ w2t,
        float* __restrict__ w_tok, int* __restrict__ e_sel) {
    __shared__ float smf[NE * GSTR];   // 32,896 B (transpose uses first 16,640 B)
    int bid = blockIdx.x;
    int tid = threadIdx.x;

    if (bid >= 2048) {
        // ---------------- transpose+cast role ----------------
        int t = bid - 2048;
        int z = t >> 7;            // 0..15
        int idx = t & 127;
        int bx = idx & 7, by = idx >> 3;
        const float* src; unsigned short* dst; int R, C, c0, r0;
        if (z < 8) {
            src = w1 + (size_t)z * DM * HE; dst = w1t + (size_t)z * DM * HE;
            R = DM; C = HE; c0 = bx * 64; r0 = by * 64;
        } else {
            int e = z - 8;
            src = w2 + (size_t)e * HE * DM; dst = w2t + (size_t)e * HE * DM;
            R = HE; C = DM; c0 = by * 64; r0 = bx * 64;
        }
        float (*tile)[65] = (float(*)[65])smf;
        int tc = tid & 63, tg = tid >> 6;
        #pragma unroll
        for (int i = 0; i < 16; i++) {
            int r = tg * 16 + i;
            tile[r][tc] = src[(size_t)(r0 + r) * C + (c0 + tc)];
        }
        __syncthreads();
        #pragma unroll
        for (int i = 0; i < 16; i++) {
            int r = tg * 16 + i;
            dst[(size_t)(c0 + r) * R + (r0 + tc)] = f2bf(tile[tc][r]);
        }
        return;
    }

    // ---------------- gate + cast role ----------------
    float* gls = smf;
    for (int v = tid; v < 2048; v += 256) {
        float4 g4 = ((const float4*)gw)[v];
        int idx = v * 4;
        int d = idx >> 3;
        int e0 = idx & 7;   // 0 or 4
        gls[(e0    ) * GSTR + d] = g4.x;
        gls[(e0 + 1) * GSTR + d] = g4.y;
        gls[(e0 + 2) * GSTR + d] = g4.z;
        gls[(e0 + 3) * GSTR + d] = g4.w;
    }
    __syncthreads();

    int n = bid * 4 + (tid >> 6);
    int lane = tid & 63;
    const float4* xr = (const float4*)(x + (size_t)n * DM);
    ushort4* xw = (ushort4*)(xb + (size_t)n * DM);

    double s[NE];
    #pragma unroll
    for (int e = 0; e < NE; e++) s[e] = 0.0;

    #pragma unroll
    for (int i = 0; i < 4; i++) {
        float4 x4 = xr[i * 64 + lane];
        ushort4 o;
        o.x = f2bf(x4.x); o.y = f2bf(x4.y); o.z = f2bf(x4.z); o.w = f2bf(x4.w);
        xw[i * 64 + lane] = o;
        int d = (i * 64 + lane) * 4;
        #pragma unroll
        for (int e = 0; e < NE; e++) {
            float4 g4 = *(const float4*)(&gls[e * GSTR + d]);
            s[e] += (double)x4.x * (double)g4.x + (double)x4.y * (double)g4.y
                  + (double)x4.z * (double)g4.z + (double)x4.w * (double)g4.w;
        }
    }
    #pragma unroll
    for (int e = 0; e < NE; e++) {
        for (int off = 32; off > 0; off >>= 1)
            s[e] += shfl_xor_dbl(s[e], off);
    }
    if (lane == 0) {
        double m = s[0];
        for (int e = 1; e < NE; e++) if (s[e] > m) m = s[e];
        double sum = 0.0;
        for (int e = 0; e < NE; e++) sum += exp(s[e] - m);
        int i1 = 0; double v1 = s[0];
        for (int e = 1; e < NE; e++) if (s[e] > v1) { v1 = s[e]; i1 = e; }
        int i2 = -1; double v2 = -1e300;
        for (int e = 0; e < NE; e++) if (e != i1 && s[e] > v2) { v2 = s[e]; i2 = e; }
        w_tok[n] = (float)((exp(v1 - m) + exp(v2 - m)) / sum);
        e_sel[2 * n]     = i1;
        e_sel[2 * n + 1] = i2;
    }
}

// ------ routing: histogram + scan + scatter + per-M-block tables, ONE block ------
__global__ __launch_bounds__(1024) void route_kernel(
        const int* __restrict__ e_sel, int* __restrict__ cnt, int* __restrict__ offs,
        int* __restrict__ pair_tok, int* __restrict__ slotmap,
        int* __restrict__ mb_e, int* __restrict__ mb_base, int* __restrict__ n_mb) {
    __shared__ int wbin[16][NE];     // per-wave bins -> later per-wave cursors
    __shared__ int wstart[16][NE];
    __shared__ int etot[NE], eoffs[NE], bofs[NE];
    int tid = threadIdx.x;
    int w = tid >> 6, l = tid & 63;
    if (l < NE) wbin[w][l] = 0;
    __syncthreads();

    int sel[16];
    #pragma unroll
    for (int k = 0; k < 16; k++) {
        sel[k] = e_sel[tid * 16 + k];
        atomicAdd(&wbin[w][sel[k]], 1);
    }
    __syncthreads();

    if (tid < NE) {
        int t = 0;
        for (int ww = 0; ww < 16; ww++) t += wbin[ww][tid];
        etot[tid] = t;
    }
    __syncthreads();
    if (tid == 0) {
        int a = 0, b = 0;
        for (int e = 0; e < NE; e++) {
            eoffs[e] = a; a += etot[e];
            bofs[e] = b;  b += (etot[e] + BM - 1) / BM;
        }
        n_mb[0] = b;
    }
    __syncthreads();
    if (tid < NE) {
        cnt[tid] = etot[tid];
        offs[tid] = eoffs[tid];
        int r = eoffs[tid];
        for (int ww = 0; ww < 16; ww++) { wstart[ww][tid] = r; r += wbin[ww][tid]; }
        int nb = (etot[tid] + BM - 1) / BM;
        int b0 = bofs[tid];
        for (int b = 0; b < nb; b++) {
            mb_e[b0 + b] = tid;
            mb_base[b0 + b] = eoffs[tid] + b * BM;
        }
    }
    __syncthreads();
    if (l < NE) wbin[w][l] = wstart[w][l];   // reuse as cursors
    __syncthreads();

    #pragma unroll
    for (int k = 0; k < 16; k++) {
        int i = tid * 16 + k;
        int slot = atomicAdd(&wbin[w][sel[k]], 1);
        pair_tok[slot] = i >> 1;
        slotmap[i] = slot;
    }
}

// ---------------- GEMM1: h = gelu(x_gathered @ w1[e] + b1[e]) ----------------
// 64x128 tile, single-buffer LDS, dense mb grid, LDS-staged coalesced epilogue.
__global__ __launch_bounds__(256, 4) void gemm1_kernel(
        const unsigned short* __restrict__ xb,      // [N_TOK][DM] bf16
        const unsigned short* __restrict__ w1t,     // [E][HE][DM] bf16 (B^T layout)
        const float* __restrict__ b1,               // [E][HE]
        const int* __restrict__ pair_tok,
        const int* __restrict__ cnt, const int* __restrict__ offs,
        const int* __restrict__ mb_e, const int* __restrict__ mb_base,
        const int* __restrict__ n_mb,
        unsigned short* __restrict__ hbuf) {        // [NPAIR][HE] bf16
    int mb = blockIdx.y;
    if (mb >= n_mb[0]) return;
    int e = mb_e[mb];
    int sbase = mb_base[mb];
    int vlim = offs[e] + cnt[e];
    int n0 = blockIdx.x * BN;

    __shared__ __align__(16) unsigned short smem[BM * BK + BN * BK];   // 24 KB
    char* As = (char*)smem;            //  8 KB
    char* Bs = (char*)smem + 8192;     // 16 KB

    int tid = threadIdx.x;
    int lane = tid & 63;
    int w = tid >> 6;
    int wu = __builtin_amdgcn_readfirstlane(w);
    int l3 = lane >> 3, l7 = lane & 7;
    int g = l7 ^ l3;               // swizzled source k-group for this lane

    const char* aptr[2];
    const char* bptr[4];
    #pragma unroll
    for (int j = 0; j < 2; j++) {
        int row = w * 16 + j * 8 + l3;
        int slot = sbase + row;
        int t = pair_tok[slot < vlim ? slot : vlim - 1];
        aptr[j] = (const char*)xb + (size_t)t * (DM * 2) + g * 16;
    }
    #pragma unroll
    for (int j = 0; j < 4; j++) {
        int row = w * 32 + j * 8 + l3;
        bptr[j] = (const char*)w1t + ((size_t)e * HE + n0 + row) * (DM * 2) + g * 16;
    }

    int wm = (w & 1) * 32;
    int wn = (w >> 1) * 64;
    int fr = lane & 15;
    int fq = lane >> 4;

    f32x4 acc[2][4];
    #pragma unroll
    for (int i = 0; i < 2; i++)
        #pragma unroll
        for (int j = 0; j < 4; j++)
            acc[i][j] = (f32x4){0.f, 0.f, 0.f, 0.f};

    for (int k0 = 0; k0 < DM; k0 += BK) {
        int kb = k0 * 2;
        #pragma unroll
        for (int j = 0; j < 2; j++)
            gl_lds16(aptr[j] + kb, As + wu * 2048 + j * 1024);
        #pragma unroll
        for (int j = 0; j < 4; j++)
            gl_lds16(bptr[j] + kb, Bs + wu * 4096 + j * 1024);
        __syncthreads();   // drains vmcnt: LDS tiles ready
        #pragma unroll
        for (int kk2 = 0; kk2 < 2; kk2++) {
            int sw = ((kk2 * 4 + fq) ^ (fr & 7)) << 4;   // swizzled byte group
            bf16x8 af[2], bfv[4];
            #pragma unroll
            for (int i = 0; i < 2; i++)
                af[i] = *(const bf16x8*)(As + (wm + i * 16 + fr) * 128 + sw);
            #pragma unroll
            for (int j = 0; j < 4; j++)
                bfv[j] = *(const bf16x8*)(Bs + (wn + j * 16 + fr) * 128 + sw);
            #pragma unroll
            for (int i = 0; i < 2; i++)
                #pragma unroll
                for (int j = 0; j < 4; j++)
                    acc[i][j] = __builtin_amdgcn_mfma_f32_16x16x32_bf16(af[i], bfv[j], acc[i][j], 0, 0, 0);
        }
        __syncthreads();   // all waves done reading before next stage overwrites
    }

    // ---- epilogue: stage to LDS (stride OSTR), then coalesced 64 B stores ----
    unsigned short* ot = smem;   // 64*136*2 = 17,408 B <= 24 KB
    #pragma unroll
    for (int j = 0; j < 4; j++) {
        int nl = wn + j * 16 + fr;
        float bias = b1[e * HE + n0 + nl];
        #pragma unroll
        for (int i = 0; i < 2; i++) {
            #pragma unroll
            for (int r = 0; r < 4; r++) {
                int mm = wm + i * 16 + fq * 4 + r;
                ot[mm * OSTR + nl] = f2bf(gelu_exact(acc[i][j][r] + bias));
            }
        }
    }
    __syncthreads();
    int row = tid >> 2;
    int c0 = (tid & 3) * 32;
    if (sbase + row < vlim) {
        const uint4* sp = (const uint4*)(ot + row * OSTR + c0);
        uint4* dp = (uint4*)(hbuf + (size_t)(sbase + row) * HE + n0 + c0);
        dp[0] = sp[0]; dp[1] = sp[1]; dp[2] = sp[2]; dp[3] = sp[3];
    }
}

// -------- GEMM2: ybuf[slot] = w_tok * (h @ w2[e] + b2[e])  (bf16, no atomics) --------
__global__ __launch_bounds__(256, 4) void gemm2_kernel(
        const unsigned short* __restrict__ hbuf,    // [NPAIR][HE] bf16
        const unsigned short* __restrict__ w2t,     // [E][DM][HE] bf16 (B^T layout)
        const float* __restrict__ b2,               // [E][DM]
        const int* __restrict__ pair_tok,
        const float* __restrict__ w_tok,
        const int* __restrict__ cnt, const int* __restrict__ offs,
        const int* __restrict__ mb_e, const int* __restrict__ mb_base,
        const int* __restrict__ n_mb,
        unsigned short* __restrict__ ybuf) {        // [NPAIR][DM] bf16
    int mb = blockIdx.y;
    if (mb >= n_mb[0]) return;
    int e = mb_e[mb];
    int sbase = mb_base[mb];
    int vlim = offs[e] + cnt[e];
    int n0 = blockIdx.x * BN;

    __shared__ __align__(16) unsigned short smem[BM * BK + BN * BK];   // 24 KB
    char* As = (char*)smem;
    char* Bs = (char*)smem + 8192;
    __shared__ float wts[BM];

    int tid = threadIdx.x;
    if (tid < BM) {
        int slot = sbase + tid;
        wts[tid] = w_tok[pair_tok[slot < vlim ? slot : vlim - 1]];
    }
    __syncthreads();

    int lane = tid & 63;
    int w = tid >> 6;
    int wu = __builtin_amdgcn_readfirstlane(w);
    int l3 = lane >> 3, l7 = lane & 7;
    int g = l7 ^ l3;

    const char* aptr[2];
    const char* bptr[4];
    #pragma unroll
    for (int j = 0; j < 2; j++) {
        int row = w * 16 + j * 8 + l3;
        int slot = sbase + row;
        int cs = (slot < vlim) ? slot : vlim - 1;   // clamp OOB rows
        aptr[j] = (const char*)hbuf + (size_t)cs * (HE * 2) + g * 16;
    }
    #pragma unroll
    for (int j = 0; j < 4; j++) {
        int row = w * 32 + j * 8 + l3;
        bptr[j] = (const char*)w2t + ((size_t)e * DM + n0 + row) * (HE * 2) + g * 16;
    }

    int wm = (w & 1) * 32;
    int wn = (w >> 1) * 64;
    int fr = lane & 15;
    int fq = lane >> 4;

    f32x4 acc[2][4];
    #pragma unroll
    for (int i = 0; i < 2; i++)
        #pragma unroll
        for (int j = 0; j < 4; j++)
            acc[i][j] = (f32x4){0.f, 0.f, 0.f, 0.f};

    for (int k0 = 0; k0 < HE; k0 += BK) {
        int kb = k0 * 2;
        #pragma unroll
        for (int j = 0; j < 2; j++)
            gl_lds16(aptr[j] + kb, As + wu * 2048 + j * 1024);
        #pragma unroll
        for (int j = 0; j < 4; j++)
            gl_lds16(bptr[j] + kb, Bs + wu * 4096 + j * 1024);
        __syncthreads();
        #pragma unroll
        for (int kk2 = 0; kk2 < 2; kk2++) {
            int sw = ((kk2 * 4 + fq) ^ (fr & 7)) << 4;
            bf16x8 af[2], bfv[4];
            #pragma unroll
            for (int i = 0; i < 2; i++)
                af[i] = *(const bf16x8*)(As + (wm + i * 16 + fr) * 128 + sw);
            #pragma unroll
            for (int j = 0; j < 4; j++)
                bfv[j] = *(const bf16x8*)(Bs + (wn + j * 16 + fr) * 128 + sw);
            #pragma unroll
            for (int i = 0; i < 2; i++)
                #pragma unroll
                for (int j = 0; j < 4; j++)
                    acc[i][j] = __builtin_amdgcn_mfma_f32_16x16x32_bf16(af[i], bfv[j], acc[i][j], 0, 0, 0);
        }
        __syncthreads();
    }

    // ---- epilogue: stage to LDS, then coalesced 64 B stores ----
    unsigned short* ot = smem;
    #pragma unroll
    for (int j = 0; j < 4; j++) {
        int nl = wn + j * 16 + fr;
        float bias = b2[e * DM + n0 + nl];
        #pragma unroll
        for (int i = 0; i < 2; i++) {
            #pragma unroll
            for (int r = 0; r < 4; r++) {
                int mm = wm + i * 16 + fq * 4 + r;
                ot[mm * OSTR + nl] = f2bf(wts[mm] * (acc[i][j][r] + bias));
            }
        }
    }
    __syncthreads();
    int row = tid >> 2;
    int c0 = (tid & 3) * 32;
    if (sbase + row < vlim) {
        const uint4* sp = (const uint4*)(ot + row * OSTR + c0);
        uint4* dp = (uint4*)(ybuf + (size_t)(sbase + row) * DM + n0 + c0);
        dp[0] = sp[0]; dp[1] = sp[1]; dp[2] = sp[2]; dp[3] = sp[3];
    }
}

// ---------------- combine: out[n] = yb[slot1] + yb[slot2] ----------------
__device__ __forceinline__ float2 bfpair(unsigned int u) {
    float2 f;
    f.x = __uint_as_float(u << 16);
    f.y = __uint_as_float(u & 0xffff0000u);
    return f;
}

__global__ void combine_kernel(const unsigned short* __restrict__ yb,
                               const int* __restrict__ slotmap,
                               float* __restrict__ out) {
    int i = blockIdx.x * 256 + threadIdx.x;   // N_TOK*DM/8 threads
    int n = i >> 7;                            // 128 8-elem groups per token
    int c = (i & 127) * 8;
    int s1 = slotmap[2 * n];
    int s2 = slotmap[2 * n + 1];
    uint4 a = *(const uint4*)(&yb[(size_t)s1 * DM + c]);
    uint4 b = *(const uint4*)(&yb[(size_t)s2 * DM + c]);
    float2 ax = bfpair(a.x), ay = bfpair(a.y), az = bfpair(a.z), aw = bfpair(a.w);
    float2 bx = bfpair(b.x), by = bfpair(b.y), bz = bfpair(b.z), bw = bfpair(b.w);
    float4 o0, o1;
    o0.x = ax.x + bx.x; o0.y = ax.y + bx.y; o0.z = ay.x + by.x; o0.w = ay.y + by.y;
    o1.x = az.x + bz.x; o1.y = az.y + bz.y; o1.z = aw.x + bw.x; o1.w = aw.y + bw.y;
    float4* dp = (float4*)(out + (size_t)n * DM + c);
    dp[0] = o0; dp[1] = o1;
}

extern "C" void kernel_launch(void* const* d_in, const int* in_sizes, int n_in,
                              void* d_out, int out_size, void* d_ws, size_t ws_size,
                              hipStream_t stream) {
    const float* x  = (const float*)d_in[0];
    const float* gw = (const float*)d_in[1];
    const float* w1 = (const float*)d_in[2];
    const float* b1 = (const float*)d_in[3];
    const float* w2 = (const float*)d_in[4];
    const float* b2 = (const float*)d_in[5];
    float* out = (float*)d_out;

    char* ws = (char*)d_ws;
    // ws layout (bytes), total ~59 MB.
    // ybuf (33.5 MB) overlays xb + w1t: both dead by the time gemm2 runs.
    unsigned short* ybuf = (unsigned short*)(ws);              // 33,554,432 [NPAIR][DM] bf16
    unsigned short* xb   = (unsigned short*)(ws);              // 16,777,216 (dead after gemm1)
    unsigned short* w1t  = (unsigned short*)(ws + 16777216);   //  8,388,608 (dead after gemm1)
    unsigned short* w2t  = (unsigned short*)(ws + 33554432);   //  8,388,608  [e][d][h]
    unsigned short* hbuf = (unsigned short*)(ws + 41943040);   // 16,777,216  [NPAIR][HE]
    float* w_tok         = (float*)(ws + 58720256);            //     32,768
    int*   e_sel         = (int*)(ws + 58753024);              //     65,536
    int*   slotmap       = (int*)(ws + 58818560);              //     65,536
    int*   cnt           = (int*)(ws + 58884096);              //         32
    int*   offs          = (int*)(ws + 58884128);              //         32
    int*   pair_tok      = (int*)(ws + 58884224);              //     65,536
    int*   mb_e          = (int*)(ws + 58949760);              //      1,088
    int*   mb_base       = (int*)(ws + 58950848);              //      1,088
    int*   n_mb          = (int*)(ws + 58951936);              //          4

    prep_kernel<<<4096, 256, 0, stream>>>(x, gw, w1, w2, xb, w1t, w2t, w_tok, e_sel);
    route_kernel<<<1, 1024, 0, stream>>>(e_sel, cnt, offs, pair_tok, slotmap,
                                         mb_e, mb_base, n_mb);
    gemm1_kernel<<<dim3(HE / BN, MAXMB), 256, 0, stream>>>(
        xb, w1t, b1, pair_tok, cnt, offs, mb_e, mb_base, n_mb, hbuf);
    gemm2_kernel<<<dim3(DM / BN, MAXMB), 256, 0, stream>>>(
        hbuf, w2t, b2, pair_tok, w_tok, cnt, offs, mb_e, mb_base, n_mb, ybuf);
    combine_kernel<<<(N_TOK * DM / 8) / 256, 256, 0, stream>>>(ybuf, slotmap, out);
}